// Round 4
// baseline (383.791 us; speedup 1.0000x reference)
//
#include <hip/hip_runtime.h>
#include <hip/hip_bf16.h>
#include <stdint.h>
#include <math.h>

// ---------------------------------------------------------------------------
// Attention_74852690035363 — f32 I/O, bf16 MFMA compute.
//   front = casts + all weight transposes + brot  [ONE z-routed launch]
//   Mprep = M GEMM (272 blk, symmetric upper-triangle only + mirrored write)
//           + Wrot/tsrT prep (1024 blk)  [ONE launch, heavy blocks first]
//   x2    = hs·M (M symmetric)          [64x128 tile, BK=128]
//   mixed = x2·Wrotᵀ + brot             [128² tile BK=64, 768 blk;
//           V block-columns ALSO emit transposed tile -> vT via LDS bounce]
//   flash = fused exp(scale·q·kᵀ) causal / rowsum / P·V -> ctx
//           (R10 pipelined structure, balanced CU pairing, XCD-affine)
//   out   = ctx·tsrTᵀ + dense_b         [64x128 tile, BK=128, f32 store]
// LDS tiles 16B-chunk XOR-swizzled.
// R12 notes: 256²-8phase gemm8p REVERTED (192 blocks = 75% CU coverage,
// B-panel refetch 102MB, MfmaUtil 23% — worse than gemm_nt128's 66µs).
// M symmetry: transposed copy is bitwise-identical (same products, same
// k-order), so only J>=I super-tiles are computed (272 vs 512 blocks).
// R13: identical to R12 source — R12 bench was an infra failure (container
// acquisition), no kernel signal. Audited for hangs: triangle decode
// terminates, all barriers block-uniform, LDS bounces fit carves exactly.
// ---------------------------------------------------------------------------

typedef __bf16 bf16_t;
typedef __bf16 bf16x8 __attribute__((ext_vector_type(8)));
typedef __bf16 bf16x4 __attribute__((ext_vector_type(4)));
typedef float  f32x4  __attribute__((ext_vector_type(4)));

__device__ __forceinline__ void async16(const void* g, void* l) {
  __builtin_amdgcn_global_load_lds(
      (const __attribute__((address_space(1))) void*)(uintptr_t)g,
      (__attribute__((address_space(3))) void*)(uint32_t)(uintptr_t)l,
      16, 0, 0);
}

#define FK_WAIT8() do { asm volatile("s_waitcnt vmcnt(8)" ::: "memory"); \
                        __builtin_amdgcn_sched_barrier(0); } while (0)
#define FK_WAIT0() do { asm volatile("s_waitcnt vmcnt(0)" ::: "memory"); \
                        __builtin_amdgcn_sched_barrier(0); } while (0)
#define FK_BAR()   do { __builtin_amdgcn_s_barrier(); \
                        __builtin_amdgcn_sched_barrier(0); } while (0)

// ---------------- 128x128-tile NT GEMM, BK=64 (for `mixed`) ----------------
// flags&8: bf16 bias.  flags&16: V-fusion — blocks with blockIdx.x%3==2 also
// write their (bias-included) tile TRANSPOSED into vT[h][e][t] via LDS bounce.
__global__ __launch_bounds__(256)
void gemm_nt128(const bf16_t* __restrict__ A, const bf16_t* __restrict__ B,
                void* __restrict__ Cv, const void* __restrict__ biasv,
                bf16_t* __restrict__ vT,
                int K, int lda, int ldb, int ldc, float alpha, int flags)
{
  const int bm0 = blockIdx.y * 128;
  const int bn0 = blockIdx.x * 128;

  __shared__ bf16_t smem[16384];   // shA 16KB | shB 16KB; reused as 128x128 tile
  bf16_t* shA = smem;
  bf16_t* shB = smem + 8192;

  const int t  = threadIdx.x;
  const int w  = t >> 6;
  const int l  = t & 63;
  const int wm = (w >> 1) * 64;
  const int wn = (w & 1) * 64;
  const int r0 = l >> 2;
  const int c0 = ((l & 3) ^ ((l >> 3) & 3)) * 8;
  const int fr = l & 15;
  const int kc = l >> 4;
  const int swr = ((fr >> 1) & 3);

  f32x4 acc[4][4];
  #pragma unroll
  for (int i = 0; i < 4; ++i)
    #pragma unroll
    for (int j = 0; j < 4; ++j)
      #pragma unroll
      for (int r = 0; r < 4; ++r)
        acc[i][j][r] = 0.0f;

  for (int k0 = 0; k0 < K; k0 += 64) {
    #pragma unroll
    for (int u = 0; u < 4; ++u) {
      const int seg  = u * 4 + w;
      const int half = seg >> 3;
      const int s8   = seg & 7;
      const int row  = s8 * 16 + r0;
      const int gk   = k0 + half * 32 + c0;
      async16(A + (long long)(bm0 + row) * lda + gk, &shA[half * 4096 + s8 * 512]);
      async16(B + (long long)(bn0 + row) * ldb + gk, &shB[half * 4096 + s8 * 512]);
    }
    __builtin_amdgcn_s_waitcnt(0);
    __syncthreads();

    const int rc = (kc ^ swr) * 8;
    #pragma unroll
    for (int h = 0; h < 2; ++h) {
      bf16x8 af[4], bfv[4];
      #pragma unroll
      for (int i = 0; i < 4; ++i) {
        af[i]  = *(const bf16x8*)&shA[h * 4096 + (wm + i * 16 + fr) * 32 + rc];
        bfv[i] = *(const bf16x8*)&shB[h * 4096 + (wn + i * 16 + fr) * 32 + rc];
      }
      #pragma unroll
      for (int i = 0; i < 4; ++i)
        #pragma unroll
        for (int j = 0; j < 4; ++j)
          acc[i][j] = __builtin_amdgcn_mfma_f32_16x16x32_bf16(af[i], bfv[j], acc[i][j], 0, 0, 0);
    }
    __syncthreads();
  }

  const int cc = l & 15;
  const int rq = (l >> 4) * 4;
  bf16_t* C = (bf16_t*)Cv;
  const bf16_t* bias = (flags & 8) ? (const bf16_t*)biasv : nullptr;
  const bool vblk = (flags & 16) && ((blockIdx.x % 3) == 2);
  #pragma unroll
  for (int j = 0; j < 4; ++j) {
    const int coll = wn + j * 16 + cc;
    const int col = bn0 + coll;
    const float bv = bias ? (float)bias[col] : 0.0f;
    #pragma unroll
    for (int i = 0; i < 4; ++i)
      #pragma unroll
      for (int r = 0; r < 4; ++r) {
        const int rowl = wm + i * 16 + rq + r;
        const bf16_t v = (bf16_t)(acc[i][j][r] * alpha + bv);
        C[(long long)(bm0 + rowl) * ldc + col] = v;
        if (vblk)
          smem[rowl * 128 + (((coll >> 3) ^ (rowl & 15)) * 8) + (coll & 7)] = v;
      }
  }

  if (vblk) {
    __syncthreads();
    const int h  = (int)blockIdx.x / 3;      // x = 3h+2 -> V block of head h
    const int e  = t >> 1;                   // 0..127
    const int t0 = (t & 1) * 64;             // row-half of the tile
    bf16_t* vp = vT + (long long)h * 262144 + (long long)e * 2048 + bm0 + t0;
    #pragma unroll
    for (int u = 0; u < 64; u += 8) {
      bf16x8 v;
      #pragma unroll
      for (int q = 0; q < 8; ++q) {
        const int r = t0 + u + q;
        v[q] = smem[r * 128 + (((e >> 3) ^ (r & 15)) * 8) + (e & 7)];
      }
      *(bf16x8*)(vp + u) = v;
    }
  }
}

// ---------------- 64x128-tile NT GEMM, BK=128 (x2 / out) -------------------
// flags&4: f32 C + f32 bias
__global__ __launch_bounds__(256)
void gemm_nt64k(const bf16_t* __restrict__ A, const bf16_t* __restrict__ B,
                void* __restrict__ Cv, const void* __restrict__ biasv,
                int K, int lda, int ldb, int ldc, float alpha, int flags)
{
  const int bm0 = blockIdx.y * 64;
  const int bn0 = blockIdx.x * 128;

  __shared__ bf16_t shA[8192];    // 4 quarters x 64x32   (16 KB)
  __shared__ bf16_t shB[16384];   // 4 quarters x 128x32  (32 KB)

  const int t  = threadIdx.x;
  const int w  = t >> 6;
  const int l  = t & 63;
  const int wm = (w >> 1) * 32;
  const int wn = (w & 1) * 64;
  const int r0 = l >> 2;
  const int c0 = ((l & 3) ^ ((l >> 3) & 3)) * 8;
  const int fr = l & 15;
  const int kc = l >> 4;
  const int swr = ((fr >> 1) & 3);

  f32x4 acc[2][4];
  #pragma unroll
  for (int i = 0; i < 2; ++i)
    #pragma unroll
    for (int j = 0; j < 4; ++j)
      #pragma unroll
      for (int r = 0; r < 4; ++r)
        acc[i][j][r] = 0.0f;

  for (int k0 = 0; k0 < K; k0 += 128) {
    #pragma unroll
    for (int u = 0; u < 4; ++u) {          // A: 16 segs (4 quarters x 4)
      const int seg = u * 4 + w;
      const int q   = seg >> 2;
      const int s4  = seg & 3;
      async16(A + (long long)(bm0 + s4 * 16 + r0) * lda + (k0 + q * 32 + c0),
              &shA[q * 2048 + s4 * 512]);
    }
    #pragma unroll
    for (int u = 0; u < 8; ++u) {          // B: 32 segs (4 quarters x 8)
      const int seg = u * 4 + w;
      const int q   = seg >> 3;
      const int s8  = seg & 7;
      async16(B + (long long)(bn0 + s8 * 16 + r0) * ldb + (k0 + q * 32 + c0),
              &shB[q * 4096 + s8 * 512]);
    }
    __builtin_amdgcn_s_waitcnt(0);
    __syncthreads();

    const int rc = (kc ^ swr) * 8;
    #pragma unroll
    for (int q = 0; q < 4; ++q) {
      bf16x8 af[2], bfv[4];
      #pragma unroll
      for (int i = 0; i < 2; ++i)
        af[i]  = *(const bf16x8*)&shA[q * 2048 + (wm + i * 16 + fr) * 32 + rc];
      #pragma unroll
      for (int j = 0; j < 4; ++j)
        bfv[j] = *(const bf16x8*)&shB[q * 4096 + (wn + j * 16 + fr) * 32 + rc];
      #pragma unroll
      for (int i = 0; i < 2; ++i)
        #pragma unroll
        for (int j = 0; j < 4; ++j)
          acc[i][j] = __builtin_amdgcn_mfma_f32_16x16x32_bf16(af[i], bfv[j], acc[i][j], 0, 0, 0);
    }
    __syncthreads();
  }

  const int cc = l & 15;
  const int rq = (l >> 4) * 4;
  if (flags & 4) {
    float* C = (float*)Cv;
    const float* bias = (const float*)biasv;
    #pragma unroll
    for (int j = 0; j < 4; ++j) {
      const int col = bn0 + wn + j * 16 + cc;
      const float bv = bias ? bias[col] : 0.0f;
      #pragma unroll
      for (int i = 0; i < 2; ++i)
        #pragma unroll
        for (int r = 0; r < 4; ++r) {
          const int row = bm0 + wm + i * 16 + rq + r;
          C[(long long)row * ldc + col] = acc[i][j][r] * alpha + bv;
        }
    }
  } else {
    bf16_t* C = (bf16_t*)Cv;
    #pragma unroll
    for (int j = 0; j < 4; ++j) {
      const int col = bn0 + wn + j * 16 + cc;
      #pragma unroll
      for (int i = 0; i < 2; ++i)
        #pragma unroll
        for (int r = 0; r < 4; ++r) {
          const int row = bm0 + wm + i * 16 + rq + r;
          C[(long long)row * ldc + col] = (bf16_t)(acc[i][j][r] * alpha);
        }
    }
  }
}

// ---------------- merged M GEMM + prep GEMMs (one launch) ------------------
// z < 272: M super-tile blocks (symmetric: only J>=I computed; off-diagonal
//          blocks mirror their tile via LDS-bounce transpose — bitwise equal).
// z >= 272: Wrot/tsrT prep (128x128, K=128), as before.
__global__ __launch_bounds__(256)
void gemm_mprep(const bf16_t* __restrict__ qkT, const bf16_t* __restrict__ vlT,
                const bf16_t* __restrict__ qkv_wT, const bf16_t* __restrict__ dwT,
                bf16_t* __restrict__ Wrot, bf16_t* __restrict__ tsrT,
                const bf16_t* __restrict__ stb, bf16_t* __restrict__ Mbuf)
{
  __shared__ bf16_t smem[16384];   // 32 KB, carved per branch
  const int z = blockIdx.x;
  const int t  = threadIdx.x;
  const int w  = t >> 6;
  const int l  = t & 63;
  const int r0 = l >> 2;
  const int c0 = ((l & 3) ^ ((l >> 3) & 3)) * 8;
  const int fr = l & 15;
  const int kc = l >> 4;
  const int swr = ((fr >> 1) & 3);
  const int cc = l & 15;
  const int rq = (l >> 4) * 4;

  if (z < 272) {
    // ------- M body: 64x128 tile, BK=64, K=2048, stb·stbᵀ, upper-tri -------
    int sup = z >> 1;
    const int h2 = z & 1;
    int I = 0;
    #pragma unroll 1
    while (sup >= 16 - I) { sup -= 16 - I; ++I; }
    const int J = I + sup;                 // J >= I
    const int bm0 = I * 128 + h2 * 64;
    const int bn0 = J * 128;
    bf16_t* shA = smem;          // 4096
    bf16_t* shB = smem + 4096;   // 8192
    const int wm = (w >> 1) * 32;
    const int wn = (w & 1) * 64;

    f32x4 acc[2][4];
    #pragma unroll
    for (int i = 0; i < 2; ++i)
      #pragma unroll
      for (int j = 0; j < 4; ++j)
        #pragma unroll
        for (int r = 0; r < 4; ++r)
          acc[i][j][r] = 0.0f;

    for (int k0 = 0; k0 < 2048; k0 += 64) {
      #pragma unroll
      for (int u = 0; u < 2; ++u) {
        const int seg  = u * 4 + w;
        const int half = seg >> 2;
        const int s4   = seg & 3;
        async16(stb + (long long)(bm0 + s4 * 16 + r0) * 2048 + (k0 + half * 32 + c0),
                &shA[half * 2048 + s4 * 512]);
      }
      #pragma unroll
      for (int u = 0; u < 4; ++u) {
        const int seg  = u * 4 + w;
        const int half = seg >> 3;
        const int s8   = seg & 7;
        async16(stb + (long long)(bn0 + s8 * 16 + r0) * 2048 + (k0 + half * 32 + c0),
                &shB[half * 4096 + s8 * 512]);
      }
      __builtin_amdgcn_s_waitcnt(0);
      __syncthreads();

      const int rc = (kc ^ swr) * 8;
      #pragma unroll
      for (int h = 0; h < 2; ++h) {
        bf16x8 af[2], bfv[4];
        #pragma unroll
        for (int i = 0; i < 2; ++i)
          af[i]  = *(const bf16x8*)&shA[h * 2048 + (wm + i * 16 + fr) * 32 + rc];
        #pragma unroll
        for (int j = 0; j < 4; ++j)
          bfv[j] = *(const bf16x8*)&shB[h * 4096 + (wn + j * 16 + fr) * 32 + rc];
        #pragma unroll
        for (int i = 0; i < 2; ++i)
          #pragma unroll
          for (int j = 0; j < 4; ++j)
            acc[i][j] = __builtin_amdgcn_mfma_f32_16x16x32_bf16(af[i], bfv[j], acc[i][j], 0, 0, 0);
      }
      __syncthreads();
    }

    const bool mir = (I != J);
    #pragma unroll
    for (int j = 0; j < 4; ++j) {
      const int coll = wn + j * 16 + cc;
      #pragma unroll
      for (int i = 0; i < 2; ++i)
        #pragma unroll
        for (int r = 0; r < 4; ++r) {
          const int rowl = wm + i * 16 + rq + r;
          const bf16_t v = (bf16_t)acc[i][j][r];
          Mbuf[(long long)(bm0 + rowl) * 2048 + bn0 + coll] = v;
          if (mir)
            smem[rowl * 128 + (((coll >> 3) ^ (rowl & 15)) * 8) + (coll & 7)] = v;
        }
    }
    if (mir) {
      __syncthreads();
      const int c  = t >> 1;             // 0..127 (orig col -> mirrored row)
      const int rh = (t & 1) * 32;       // 32-col half
      bf16_t* mp = Mbuf + (long long)(bn0 + c) * 2048 + bm0 + rh;
      #pragma unroll
      for (int u = 0; u < 32; u += 8) {
        bf16x8 v;
        #pragma unroll
        for (int q = 0; q < 8; ++q) {
          const int r = rh + u + q;
          v[q] = smem[r * 128 + (((c >> 3) ^ (r & 15)) * 8) + (c & 7)];
        }
        *(bf16x8*)(mp + u) = v;
      }
    }
  } else {
    // ---------------- prep body: 128x128, BK=64, K=128 ----------------
    const int zz = z - 272;
    const int pz = zz >> 4, px = zz & 15;
    const bf16_t* A;
    const bf16_t* B;
    bf16_t* C;
    int bm0, bn0;
    if (pz < 48) {
      const int h = pz / 3, p = pz - 3 * h;
      A = (p == 2 ? vlT : qkT) + h * 16384;
      B = qkv_wT + (long long)pz * 262144;
      C = Wrot + (long long)pz * 262144;
      bm0 = 0;  bn0 = px * 128;
    } else {
      const int b = pz - 48;
      A = dwT + (long long)b * 262144;
      B = vlT + b * 16384;
      C = tsrT;
      bm0 = px * 128;  bn0 = b * 128;
    }
    bf16_t* shA = smem;          // 8192
    bf16_t* shB = smem + 8192;   // 8192
    const int wm = (w >> 1) * 64;
    const int wn = (w & 1) * 64;
    const int arow0 = (pz < 48 ? 0 : bm0);
    const int brow0 = (pz < 48 ? bn0 : 0);

    f32x4 acc[4][4];
    #pragma unroll
    for (int i = 0; i < 4; ++i)
      #pragma unroll
      for (int j = 0; j < 4; ++j)
        #pragma unroll
        for (int r = 0; r < 4; ++r)
          acc[i][j][r] = 0.0f;

    for (int k0 = 0; k0 < 128; k0 += 64) {
      #pragma unroll
      for (int u = 0; u < 4; ++u) {
        const int seg  = u * 4 + w;
        const int half = seg >> 3;
        const int s8   = seg & 7;
        const int row  = s8 * 16 + r0;
        const int gk   = k0 + half * 32 + c0;
        async16(A + (long long)(arow0 + row) * 128 + gk, &shA[half * 4096 + s8 * 512]);
        async16(B + (long long)(brow0 + row) * 128 + gk, &shB[half * 4096 + s8 * 512]);
      }
      __builtin_amdgcn_s_waitcnt(0);
      __syncthreads();

      const int rc = (kc ^ swr) * 8;
      #pragma unroll
      for (int h = 0; h < 2; ++h) {
        bf16x8 af[4], bfv[4];
        #pragma unroll
        for (int i = 0; i < 4; ++i) {
          af[i]  = *(const bf16x8*)&shA[h * 4096 + (wm + i * 16 + fr) * 32 + rc];
          bfv[i] = *(const bf16x8*)&shB[h * 4096 + (wn + i * 16 + fr) * 32 + rc];
        }
        #pragma unroll
        for (int i = 0; i < 4; ++i)
          #pragma unroll
          for (int j = 0; j < 4; ++j)
            acc[i][j] = __builtin_amdgcn_mfma_f32_16x16x32_bf16(af[i], bfv[j], acc[i][j], 0, 0, 0);
      }
      __syncthreads();
    }

    #pragma unroll
    for (int j = 0; j < 4; ++j) {
      const int col = bn0 + wn + j * 16 + cc;
      #pragma unroll
      for (int i = 0; i < 4; ++i)
        #pragma unroll
        for (int r = 0; r < 4; ++r) {
          const int row = arow0 + wm + i * 16 + rq + r;
          C[(long long)row * 2048 + col] = (bf16_t)acc[i][j][r];
        }
    }
  }
}

// ---------------------------------------------------------------------------
// Flash attention: one block = 64 q-rows x one head, pipelined single-buffer.
// Grid (x=head=16, y=0..31): qt = y<16 ? 31-y : y-16 -> blocks i and i+256
// (same CU under round-robin) always sum to 17 iterations (balanced).
// XCD = (h + 16y) % 8 = h % 8 -> all q-tiles of a head share one XCD L2.
// ---------------------------------------------------------------------------
__device__ __forceinline__ void stage128(const bf16_t* __restrict__ gp, bf16_t* lds,
                                         const long long rstride, const int w, const int l)
{
  #pragma unroll
  for (int s = 0; s < 8; ++s) {
    const int chunk = (w * 8 + s) * 64 + l;
    const int r = chunk >> 4;
    const int c = (chunk & 15) ^ (r & 7);
    async16(gp + (long long)r * rstride + c * 8, &lds[(w * 8 + s) * 512]);
  }
}

__global__ __launch_bounds__(256)
void flash_k(const bf16_t* __restrict__ mixed, const bf16_t* __restrict__ vT,
             bf16_t* __restrict__ ctx, float iscale)
{
  const int h  = blockIdx.x;
  const int y  = blockIdx.y;
  const int qt = (y < 16) ? (31 - y) : (y - 16);   // complementary CU pairing
  const int r0g = qt * 64;
  const int niter = (qt >> 1) + 1;
  const bf16_t* Qp = mixed + h * 384;
  const bf16_t* Kp = mixed + h * 384 + 128;
  const bf16_t* Vp = vT + (long long)h * 262144;

  __shared__ bf16_t sK[16384];   // 128 kv-rows x 128 d, chunk-XOR swizzled
  __shared__ bf16_t sV[16384];   // 128 e-rows  x 128 kv, chunk-XOR swizzled
  __shared__ bf16_t sP[8192];    // 64 q-rows x 128 kv, chunk-XOR swizzled

  const int t  = threadIdx.x;
  const int w  = t >> 6;
  const int l  = t & 63;
  const int fr = l & 15;
  const int kc = l >> 4;
  const int qrow0 = r0g + w * 16;        // this wave's first global q-row

  // Q fragments for the wave's 16 rows: lane holds row fr, k = ks*32 + kc*8
  bf16x8 aq[4];
  #pragma unroll
  for (int ks = 0; ks < 4; ++ks)
    aq[ks] = *(const bf16x8*)(Qp + (long long)(qrow0 + fr) * 6144 + ks * 32 + kc * 8);

  f32x4 oacc[8];
  #pragma unroll
  for (int j = 0; j < 8; ++j)
    #pragma unroll
    for (int r = 0; r < 4; ++r) oacc[j][r] = 0.0f;
  float lsum[4] = {0.f, 0.f, 0.f, 0.f};

  // drain the aq global loads so in-loop vmcnt counts only the async stages
  FK_WAIT0();

  stage128(Kp, sK, 6144, w, l);          // K tile 0
  stage128(Vp, sV, 2048, w, l);          // V tile 0 (cols t0=0)
  FK_WAIT8();                            // K0 landed, V0 (8) in flight
  FK_BAR();

  for (int it = 0; it < niter; ++it) {
    const int t0 = it * 128;

    // ---------------- QK (V(it) loads in flight) ----------------
    f32x4 acc[8];
    #pragma unroll
    for (int j = 0; j < 8; ++j)
      #pragma unroll
      for (int r = 0; r < 4; ++r) acc[j][r] = 0.0f;
    #pragma unroll
    for (int ks = 0; ks < 4; ++ks) {
      bf16x8 bk[8];
      #pragma unroll
      for (int j = 0; j < 8; ++j)
        bk[j] = *(const bf16x8*)&sK[(j * 16 + fr) * 128 + (((ks * 4 + kc) ^ (fr & 7)) * 8)];
      __builtin_amdgcn_s_setprio(1);
      #pragma unroll
      for (int j = 0; j < 8; ++j)
        acc[j] = __builtin_amdgcn_mfma_f32_16x16x32_bf16(aq[ks], bk[j], acc[j], 0, 0, 0);
      __builtin_amdgcn_s_setprio(0);
    }

    // ---------------- softmax (wave-local rows) ----------------
    #pragma unroll
    for (int r = 0; r < 4; ++r) {
      const int q16 = kc * 4 + r;              // row within wave's 16
      const int Rg  = qrow0 + q16;             // global q row
      float rs = 0.f;
      #pragma unroll
      for (int j = 0; j < 8; ++j) {
        const float e = (t0 + j * 16 + fr <= Rg) ? __expf(acc[j][r] * iscale) : 0.0f;
        rs += e;
        sP[(w * 16 + q16) * 128 + (((j * 2 + (fr >> 3)) ^ (q16 & 7)) * 8) + (fr & 7)] = (bf16_t)e;
      }
      rs += __shfl_xor(rs, 1, 64);
      rs += __shfl_xor(rs, 2, 64);
      rs += __shfl_xor(rs, 4, 64);
      rs += __shfl_xor(rs, 8, 64);
      lsum[r] += rs;
    }

    FK_BAR();                              // all waves done reading sK
    if (it + 1 < niter) {
      stage128(Kp + (long long)(t0 + 128) * 6144, sK, 6144, w, l);  // K(t+1) || PV
      FK_WAIT8();                          // V(it) landed (K(t+1) in flight)
    } else {
      FK_WAIT0();                          // V(it) landed
    }
    FK_BAR();                              // V(it) visible to all waves

    // ---------------- PV (K(it+1) loads in flight) ----------------
    #pragma unroll
    for (int ks = 0; ks < 4; ++ks) {
      const bf16x8 ap =
          *(const bf16x8*)&sP[(w * 16 + fr) * 128 + (((ks * 4 + kc) ^ (fr & 7)) * 8)];
      bf16x8 bv[8];
      #pragma unroll
      for (int j = 0; j < 8; ++j)
        bv[j] = *(const bf16x8*)&sV[(j * 16 + fr) * 128 + (((ks * 4 + kc) ^ (fr & 7)) * 8)];
      __builtin_amdgcn_s_setprio(1);
      #pragma unroll
      for (int j = 0; j < 8; ++j)
        oacc[j] = __builtin_amdgcn_mfma_f32_16x16x32_bf16(ap, bv[j], oacc[j], 0, 0, 0);
      __builtin_amdgcn_s_setprio(0);
    }

    if (it + 1 < niter) {
      FK_BAR();                            // all waves done reading sV
      stage128(Vp + (t0 + 128), sV, 2048, w, l);                    // V(t+1) || next QK
      FK_WAIT8();                          // K(it+1) landed (V(t+1) in flight)
      FK_BAR();                            // K(it+1) visible to all waves
    }
  }

  #pragma unroll
  for (int r = 0; r < 4; ++r) {
    const float inv = 1.0f / lsum[r];
    const int rowg = qrow0 + kc * 4 + r;
    #pragma unroll
    for (int j = 0; j < 8; ++j)
      ctx[(long long)rowg * 2048 + h * 128 + j * 16 + fr] = (bf16_t)(oacc[j][r] * inv);
  }
}

// ---------------------------------------------------------------------------
// front: z-routed mega-kernel, fully parallel (one tile per block).
// ---------------------------------------------------------------------------
__global__ __launch_bounds__(256)
void front_k(const float* __restrict__ hs, bf16_t* __restrict__ hsb,
             const float* __restrict__ svd_tok, bf16_t* __restrict__ stb,
             const float* __restrict__ svd_qk, bf16_t* __restrict__ qkT,
             const float* __restrict__ svd_vl, bf16_t* __restrict__ vlT,
             const float* __restrict__ qkv_w, bf16_t* __restrict__ qkv_wT,
             const float* __restrict__ dense_w, bf16_t* __restrict__ dwT,
             const float* __restrict__ qkv_b, bf16_t* __restrict__ brot)
{
  __shared__ bf16_t sm[32][33];
  const int z = blockIdx.x;
  const int tid = threadIdx.x;

  if (z < 2048) {
    const float* in = (z < 1024) ? hs : svd_tok;
    bf16_t* out = (z < 1024) ? hsb : stb;
    const int base = (z & 1023) * 4096 + tid * 16;
    #pragma unroll
    for (int j = 0; j < 4; ++j) {
      const f32x4 v = *(const f32x4*)(in + base + j * 4);
      bf16x4 o;
      #pragma unroll
      for (int k = 0; k < 4; ++k) o[k] = (bf16_t)v[k];
      *(bf16x4*)(out + base + j * 4) = o;
    }
  } else if (z < 2560) {
    const int zz = z - 2048;
    const int zr = zz >> 4;                 // 0..31
    const int tile = zz & 15;
    const float* ip = (zr < 16 ? svd_qk : svd_vl) + (long long)(zr & 15) * 16384;
    bf16_t* op = (zr < 16 ? qkT : vlT) + (long long)(zr & 15) * 16384;
    const int r0 = (tile & 3) << 5;
    const int c0 = (tile >> 2) << 5;
    const int tx = tid & 31;
    const int ty = tid >> 5;
    #pragma unroll
    for (int yy = ty; yy < 32; yy += 8)
      sm[yy][tx] = (bf16_t)ip[(long long)(r0 + yy) * 128 + c0 + tx];
    __syncthreads();
    #pragma unroll
    for (int yy = ty; yy < 32; yy += 8)
      op[(long long)(c0 + yy) * 128 + r0 + tx] = sm[tx][yy];
  } else if (z < 18944) {
    const int zz = z - 2560;
    const int zb = zz >> 8;                 // batch 0..63
    const int tile = zz & 255;              // 4 r-tiles x 64 c-tiles
    const float* ip = (zb < 48) ? qkv_w + (long long)zb * 262144
                                : dense_w + (long long)(zb - 48) * 262144;
    bf16_t* op = (zb < 48) ? qkv_wT + (long long)zb * 262144
                           : dwT + (long long)(zb - 48) * 262144;
    const int r0 = (tile & 3) << 5;
    const int c0 = (tile >> 2) << 5;
    const int tx = tid & 31;
    const int ty = tid >> 5;
    #pragma unroll
    for (int yy = ty; yy < 32; yy += 8)
      sm[yy][tx] = (bf16_t)ip[(long long)(r0 + yy) * 2048 + c0 + tx];
    __syncthreads();
    #pragma unroll
    for (int yy = ty; yy < 32; yy += 8)
      op[(long long)(c0 + yy) * 128 + r0 + tx] = sm[tx][yy];
  } else {
    const int hp = (z - 18944) * 2 + (tid >> 7);   // 0..47
    const int h = hp / 3, p = hp % 3;
    const int e = tid & 127;
    const float* R = (p == 2 ? (const float*)svd_vl : (const float*)svd_qk) + (long long)h * 16384;
    const float* b = qkv_b + h * 384 + p * 128;
    float acc = 0.f;
    for (int d = 0; d < 128; ++d)
      acc += b[d] * R[d * 128 + e];
    brot[h * 384 + p * 128 + e] = (bf16_t)acc;
  }
}

extern "C" void kernel_launch(void* const* d_in, const int* in_sizes, int n_in,
                              void* d_out, int out_size, void* d_ws, size_t ws_size,
                              hipStream_t stream)
{
  const float* hs      = (const float*)d_in[0];
  const float* qkv_w   = (const float*)d_in[2];
  const float* qkv_b   = (const float*)d_in[3];
  const float* svd_tok = (const float*)d_in[4];
  const float* svd_qk  = (const float*)d_in[5];
  const float* svd_vl  = (const float*)d_in[6];
  const float* dense_w = (const float*)d_in[7];
  const float* dense_b = (const float*)d_in[8];
  float* out = (float*)d_out;
  bf16_t* ws = (bf16_t*)d_ws;

  bf16_t* hsb    = ws;                    //  4,194,304
  bf16_t* stb    = ws +  4194304LL;       //  4,194,304
  bf16_t* Mbuf   = ws +  8388608LL;       //  4,194,304
  bf16_t* x2     = ws + 12582912LL;       //  4,194,304
  bf16_t* qkv_wT = ws + 16777216LL;       // 12,582,912
  bf16_t* Wrot   = ws + 29360128LL;       // 12,582,912
  bf16_t* mixed  = ws + 41943040LL;       // 12,582,912
  bf16_t* vT     = ws + 54525952LL;       //  4,194,304
  bf16_t* ctx    = ws + 58720256LL;       //  4,194,304
  bf16_t* dwT    = ws + 62914560LL;       //  4,194,304
  bf16_t* tsrT   = ws + 67108864LL;       //  4,194,304
  bf16_t* qkT    = ws + 71303168LL;       //    262,144
  bf16_t* vlT    = ws + 71565312LL;       //    262,144
  bf16_t* brot   = ws + 71827456LL;       //      6,144
  if (ws_size < 71833600ULL * 2ULL) return;

  const float iscale = 0.08838834764831845f;   // 1/sqrt(128)

  // all memory-bound prep in one launch (one tile per block, no serial tail)
  front_k<<<dim3(18968), 256, 0, stream>>>(hs, hsb, svd_tok, stb,
      svd_qk, qkT, svd_vl, vlT, qkv_w, qkv_wT, dense_w, dwT, qkv_b, brot);
  // M GEMM (272 symmetric blocks, heavy-first) + Wrot/tsrT prep in one launch
  gemm_mprep<<<dim3(1296), 256, 0, stream>>>(qkT, vlT, qkv_wT, dwT,
      Wrot, tsrT, stb, Mbuf);
  // x2 = hs @ M  (M symmetric -> NT ok), BK=128
  gemm_nt64k<<<dim3(16, 32), 256, 0, stream>>>(hsb, Mbuf, x2, nullptr,
      2048, 2048, 2048, 2048, 1.0f, 0);
  // mixed = x2 @ Wrot^T + brot  (128^2 tile, BK=64); V blocks also emit vT
  gemm_nt128<<<dim3(48, 16), 256, 0, stream>>>(x2, Wrot, mixed, brot, vT,
      2048, 2048, 2048, 6144, 1.0f, 8 | 16);
  // fused attention -> ctx (balanced pairing + pipelined loads)
  flash_k<<<dim3(16, 32), 256, 0, stream>>>(mixed, vT, ctx, iscale);
  // out = ctx @ tsrT^T + dense_b  (f32 store), BK=128
  gemm_nt64k<<<dim3(16, 32), 256, 0, stream>>>(ctx, tsrT, out, dense_b,
      2048, 2048, 2048, 2048, 1.0f, 4);
}

// Round 5
// 380.186 us; speedup vs baseline: 1.0095x; 1.0095x over previous
//
#include <hip/hip_runtime.h>
#include <hip/hip_bf16.h>
#include <stdint.h>
#include <math.h>

// ---------------------------------------------------------------------------
// Attention_74852690035363 — f32 I/O, bf16 MFMA compute.
//   front = casts + all weight transposes + brot  [ONE z-routed launch]
//   Mprep = M GEMM (272 blk, symmetric upper-triangle only + mirrored write)
//           + Wrot/tsrT prep (1024 blk)  [ONE launch, heavy blocks first]
//   x2    = hs·M (M symmetric)          [64x128 tile, BK=128]
//   mixed = x2·Wrotᵀ + brot             [128² tile BK=64, 768 blk;
//           V block-columns ALSO emit transposed tile -> vT via LDS bounce]
//   flash = fused exp(scale·q·kᵀ) causal / rowsum / P·V -> ctx
//   out   = ctx·tsrTᵀ + dense_b         [64x128 tile, BK=128, f32 store]
// R14: fixed the R4 regression — vT/mirror LDS bounce now stores TRANSPOSED
// (chunk-XOR layout), so global writes are row-coalesced (16 lanes x 16B
// contiguous per wave-instr; R4's 4KB-lane-stride stores caused +14MB of
// write-allocate FETCH and 94µs vs 66µs) and read-out is vector bf16x8.
// ---------------------------------------------------------------------------

typedef __bf16 bf16_t;
typedef __bf16 bf16x8 __attribute__((ext_vector_type(8)));
typedef __bf16 bf16x4 __attribute__((ext_vector_type(4)));
typedef float  f32x4  __attribute__((ext_vector_type(4)));

__device__ __forceinline__ void async16(const void* g, void* l) {
  __builtin_amdgcn_global_load_lds(
      (const __attribute__((address_space(1))) void*)(uintptr_t)g,
      (__attribute__((address_space(3))) void*)(uint32_t)(uintptr_t)l,
      16, 0, 0);
}

#define FK_WAIT8() do { asm volatile("s_waitcnt vmcnt(8)" ::: "memory"); \
                        __builtin_amdgcn_sched_barrier(0); } while (0)
#define FK_WAIT0() do { asm volatile("s_waitcnt vmcnt(0)" ::: "memory"); \
                        __builtin_amdgcn_sched_barrier(0); } while (0)
#define FK_BAR()   do { __builtin_amdgcn_s_barrier(); \
                        __builtin_amdgcn_sched_barrier(0); } while (0)

// ---------------- 128x128-tile NT GEMM, BK=64 (for `mixed`) ----------------
// flags&8: bf16 bias.  flags&16: V-fusion — blocks with blockIdx.x%3==2 also
// write their (bias-included) tile TRANSPOSED into vT[h][e][t].
// Bounce layout: element (m,e) of the tile lives at
//   smem[e*128 + ((m>>3)^(e&15))*8 + (m&7)]
// -> read-out of 8 consecutive m for fixed e is ONE contiguous bf16x8.
__global__ __launch_bounds__(256)
void gemm_nt128(const bf16_t* __restrict__ A, const bf16_t* __restrict__ B,
                void* __restrict__ Cv, const void* __restrict__ biasv,
                bf16_t* __restrict__ vT,
                int K, int lda, int ldb, int ldc, float alpha, int flags)
{
  const int bm0 = blockIdx.y * 128;
  const int bn0 = blockIdx.x * 128;

  __shared__ bf16_t smem[16384];   // shA 16KB | shB 16KB; reused as 128x128 tile
  bf16_t* shA = smem;
  bf16_t* shB = smem + 8192;

  const int t  = threadIdx.x;
  const int w  = t >> 6;
  const int l  = t & 63;
  const int wm = (w >> 1) * 64;
  const int wn = (w & 1) * 64;
  const int r0 = l >> 2;
  const int c0 = ((l & 3) ^ ((l >> 3) & 3)) * 8;
  const int fr = l & 15;
  const int kc = l >> 4;
  const int swr = ((fr >> 1) & 3);

  f32x4 acc[4][4];
  #pragma unroll
  for (int i = 0; i < 4; ++i)
    #pragma unroll
    for (int j = 0; j < 4; ++j)
      #pragma unroll
      for (int r = 0; r < 4; ++r)
        acc[i][j][r] = 0.0f;

  for (int k0 = 0; k0 < K; k0 += 64) {
    #pragma unroll
    for (int u = 0; u < 4; ++u) {
      const int seg  = u * 4 + w;
      const int half = seg >> 3;
      const int s8   = seg & 7;
      const int row  = s8 * 16 + r0;
      const int gk   = k0 + half * 32 + c0;
      async16(A + (long long)(bm0 + row) * lda + gk, &shA[half * 4096 + s8 * 512]);
      async16(B + (long long)(bn0 + row) * ldb + gk, &shB[half * 4096 + s8 * 512]);
    }
    __builtin_amdgcn_s_waitcnt(0);
    __syncthreads();

    const int rc = (kc ^ swr) * 8;
    #pragma unroll
    for (int h = 0; h < 2; ++h) {
      bf16x8 af[4], bfv[4];
      #pragma unroll
      for (int i = 0; i < 4; ++i) {
        af[i]  = *(const bf16x8*)&shA[h * 4096 + (wm + i * 16 + fr) * 32 + rc];
        bfv[i] = *(const bf16x8*)&shB[h * 4096 + (wn + i * 16 + fr) * 32 + rc];
      }
      #pragma unroll
      for (int i = 0; i < 4; ++i)
        #pragma unroll
        for (int j = 0; j < 4; ++j)
          acc[i][j] = __builtin_amdgcn_mfma_f32_16x16x32_bf16(af[i], bfv[j], acc[i][j], 0, 0, 0);
    }
    __syncthreads();
  }

  const int cc = l & 15;
  const int rq = (l >> 4) * 4;
  bf16_t* C = (bf16_t*)Cv;
  const bf16_t* bias = (flags & 8) ? (const bf16_t*)biasv : nullptr;
  const bool vblk = (flags & 16) && ((blockIdx.x % 3) == 2);
  #pragma unroll
  for (int j = 0; j < 4; ++j) {
    const int coll = wn + j * 16 + cc;
    const int col = bn0 + coll;
    const float bv = bias ? (float)bias[col] : 0.0f;
    #pragma unroll
    for (int i = 0; i < 4; ++i)
      #pragma unroll
      for (int r = 0; r < 4; ++r) {
        const int rowl = wm + i * 16 + rq + r;
        const bf16_t v = (bf16_t)(acc[i][j][r] * alpha + bv);
        C[(long long)(bm0 + rowl) * ldc + col] = v;
        if (vblk)   // transposed store: (m=rowl, e=coll)
          smem[coll * 128 + (((rowl >> 3) ^ (coll & 15)) * 8) + (rowl & 7)] = v;
      }
  }

  if (vblk) {
    __syncthreads();
    const int h   = (int)blockIdx.x / 3;   // x = 3h+2 -> V block of head h
    const int er  = t >> 4;                // 0..15 (row within pass)
    const int mc8 = t & 15;                // 16B chunk within row
    bf16_t* vp = vT + (long long)h * 262144 + bm0 + mc8 * 8;
    #pragma unroll
    for (int p = 0; p < 8; ++p) {
      const int e = p * 16 + er;
      const bf16x8 v = *(const bf16x8*)&smem[e * 128 + ((mc8 ^ (e & 15)) * 8)];
      *(bf16x8*)(vp + (long long)e * 2048) = v;
    }
  }
}

// ---------------- 64x128-tile NT GEMM, BK=128 (x2 / out) -------------------
// flags&4: f32 C + f32 bias
__global__ __launch_bounds__(256)
void gemm_nt64k(const bf16_t* __restrict__ A, const bf16_t* __restrict__ B,
                void* __restrict__ Cv, const void* __restrict__ biasv,
                int K, int lda, int ldb, int ldc, float alpha, int flags)
{
  const int bm0 = blockIdx.y * 64;
  const int bn0 = blockIdx.x * 128;

  __shared__ bf16_t shA[8192];    // 4 quarters x 64x32   (16 KB)
  __shared__ bf16_t shB[16384];   // 4 quarters x 128x32  (32 KB)

  const int t  = threadIdx.x;
  const int w  = t >> 6;
  const int l  = t & 63;
  const int wm = (w >> 1) * 32;
  const int wn = (w & 1) * 64;
  const int r0 = l >> 2;
  const int c0 = ((l & 3) ^ ((l >> 3) & 3)) * 8;
  const int fr = l & 15;
  const int kc = l >> 4;
  const int swr = ((fr >> 1) & 3);

  f32x4 acc[2][4];
  #pragma unroll
  for (int i = 0; i < 2; ++i)
    #pragma unroll
    for (int j = 0; j < 4; ++j)
      #pragma unroll
      for (int r = 0; r < 4; ++r)
        acc[i][j][r] = 0.0f;

  for (int k0 = 0; k0 < K; k0 += 128) {
    #pragma unroll
    for (int u = 0; u < 4; ++u) {          // A: 16 segs (4 quarters x 4)
      const int seg = u * 4 + w;
      const int q   = seg >> 2;
      const int s4  = seg & 3;
      async16(A + (long long)(bm0 + s4 * 16 + r0) * lda + (k0 + q * 32 + c0),
              &shA[q * 2048 + s4 * 512]);
    }
    #pragma unroll
    for (int u = 0; u < 8; ++u) {          // B: 32 segs (4 quarters x 8)
      const int seg = u * 4 + w;
      const int q   = seg >> 3;
      const int s8  = seg & 7;
      async16(B + (long long)(bn0 + s8 * 16 + r0) * ldb + (k0 + q * 32 + c0),
              &shB[q * 4096 + s8 * 512]);
    }
    __builtin_amdgcn_s_waitcnt(0);
    __syncthreads();

    const int rc = (kc ^ swr) * 8;
    #pragma unroll
    for (int q = 0; q < 4; ++q) {
      bf16x8 af[2], bfv[4];
      #pragma unroll
      for (int i = 0; i < 2; ++i)
        af[i]  = *(const bf16x8*)&shA[q * 2048 + (wm + i * 16 + fr) * 32 + rc];
      #pragma unroll
      for (int j = 0; j < 4; ++j)
        bfv[j] = *(const bf16x8*)&shB[q * 4096 + (wn + j * 16 + fr) * 32 + rc];
      #pragma unroll
      for (int i = 0; i < 2; ++i)
        #pragma unroll
        for (int j = 0; j < 4; ++j)
          acc[i][j] = __builtin_amdgcn_mfma_f32_16x16x32_bf16(af[i], bfv[j], acc[i][j], 0, 0, 0);
    }
    __syncthreads();
  }

  const int cc = l & 15;
  const int rq = (l >> 4) * 4;
  if (flags & 4) {
    float* C = (float*)Cv;
    const float* bias = (const float*)biasv;
    #pragma unroll
    for (int j = 0; j < 4; ++j) {
      const int col = bn0 + wn + j * 16 + cc;
      const float bv = bias ? bias[col] : 0.0f;
      #pragma unroll
      for (int i = 0; i < 2; ++i)
        #pragma unroll
        for (int r = 0; r < 4; ++r) {
          const int row = bm0 + wm + i * 16 + rq + r;
          C[(long long)row * ldc + col] = acc[i][j][r] * alpha + bv;
        }
    }
  } else {
    bf16_t* C = (bf16_t*)Cv;
    #pragma unroll
    for (int j = 0; j < 4; ++j) {
      const int col = bn0 + wn + j * 16 + cc;
      #pragma unroll
      for (int i = 0; i < 2; ++i)
        #pragma unroll
        for (int r = 0; r < 4; ++r) {
          const int row = bm0 + wm + i * 16 + rq + r;
          C[(long long)row * ldc + col] = (bf16_t)(acc[i][j][r] * alpha);
        }
    }
  }
}

// ---------------- merged M GEMM + prep GEMMs (one launch) ------------------
// z < 272: M super-tile blocks (symmetric: only J>=I computed; off-diagonal
//          blocks mirror their 64x128 tile via transposed-LDS bounce).
// z >= 272: Wrot/tsrT prep (128x128, K=128), as before.
__global__ __launch_bounds__(256)
void gemm_mprep(const bf16_t* __restrict__ qkT, const bf16_t* __restrict__ vlT,
                const bf16_t* __restrict__ qkv_wT, const bf16_t* __restrict__ dwT,
                bf16_t* __restrict__ Wrot, bf16_t* __restrict__ tsrT,
                const bf16_t* __restrict__ stb, bf16_t* __restrict__ Mbuf)
{
  __shared__ bf16_t smem[16384];   // 32 KB, carved per branch
  const int z = blockIdx.x;
  const int t  = threadIdx.x;
  const int w  = t >> 6;
  const int l  = t & 63;
  const int r0 = l >> 2;
  const int c0 = ((l & 3) ^ ((l >> 3) & 3)) * 8;
  const int fr = l & 15;
  const int kc = l >> 4;
  const int swr = ((fr >> 1) & 3);
  const int cc = l & 15;
  const int rq = (l >> 4) * 4;

  if (z < 272) {
    // ------- M body: 64x128 tile, BK=64, K=2048, stb·stbᵀ, upper-tri -------
    int sup = z >> 1;
    const int h2 = z & 1;
    int I = 0;
    #pragma unroll 1
    while (sup >= 16 - I) { sup -= 16 - I; ++I; }
    const int J = I + sup;                 // J >= I
    const int bm0 = I * 128 + h2 * 64;
    const int bn0 = J * 128;
    bf16_t* shA = smem;          // 4096
    bf16_t* shB = smem + 4096;   // 8192
    const int wm = (w >> 1) * 32;
    const int wn = (w & 1) * 64;

    f32x4 acc[2][4];
    #pragma unroll
    for (int i = 0; i < 2; ++i)
      #pragma unroll
      for (int j = 0; j < 4; ++j)
        #pragma unroll
        for (int r = 0; r < 4; ++r)
          acc[i][j][r] = 0.0f;

    for (int k0 = 0; k0 < 2048; k0 += 64) {
      #pragma unroll
      for (int u = 0; u < 2; ++u) {
        const int seg  = u * 4 + w;
        const int half = seg >> 2;
        const int s4   = seg & 3;
        async16(stb + (long long)(bm0 + s4 * 16 + r0) * 2048 + (k0 + half * 32 + c0),
                &shA[half * 2048 + s4 * 512]);
      }
      #pragma unroll
      for (int u = 0; u < 4; ++u) {
        const int seg  = u * 4 + w;
        const int half = seg >> 3;
        const int s8   = seg & 7;
        async16(stb + (long long)(bn0 + s8 * 16 + r0) * 2048 + (k0 + half * 32 + c0),
                &shB[half * 4096 + s8 * 512]);
      }
      __builtin_amdgcn_s_waitcnt(0);
      __syncthreads();

      const int rc = (kc ^ swr) * 8;
      #pragma unroll
      for (int h = 0; h < 2; ++h) {
        bf16x8 af[2], bfv[4];
        #pragma unroll
        for (int i = 0; i < 2; ++i)
          af[i]  = *(const bf16x8*)&shA[h * 2048 + (wm + i * 16 + fr) * 32 + rc];
        #pragma unroll
        for (int j = 0; j < 4; ++j)
          bfv[j] = *(const bf16x8*)&shB[h * 4096 + (wn + j * 16 + fr) * 32 + rc];
        #pragma unroll
        for (int i = 0; i < 2; ++i)
          #pragma unroll
          for (int j = 0; j < 4; ++j)
            acc[i][j] = __builtin_amdgcn_mfma_f32_16x16x32_bf16(af[i], bfv[j], acc[i][j], 0, 0, 0);
      }
      __syncthreads();
    }

    const bool mir = (I != J);
    #pragma unroll
    for (int j = 0; j < 4; ++j) {
      const int coll = wn + j * 16 + cc;
      #pragma unroll
      for (int i = 0; i < 2; ++i)
        #pragma unroll
        for (int r = 0; r < 4; ++r) {
          const int rowl = wm + i * 16 + rq + r;
          const bf16_t v = (bf16_t)acc[i][j][r];
          Mbuf[(long long)(bm0 + rowl) * 2048 + bn0 + coll] = v;
          if (mir)   // transposed store: 64-elem rows, chunk-XOR
            smem[coll * 64 + (((rowl >> 3) ^ (coll & 7)) * 8) + (rowl & 7)] = v;
        }
    }
    if (mir) {
      __syncthreads();
      // coalesced mirror write: 8 lanes x 16B cover one 128B row of M^T tile
      const int cr  = t >> 3;              // row within pass (0..31)
      const int mc8 = t & 7;               // 16B chunk within row
      bf16_t* mp = Mbuf + bm0 + mc8 * 8;
      #pragma unroll
      for (int p = 0; p < 4; ++p) {
        const int c = p * 32 + cr;         // 0..127 (col of orig = row of mirror)
        const bf16x8 v = *(const bf16x8*)&smem[c * 64 + ((mc8 ^ (c & 7)) * 8)];
        *(bf16x8*)(mp + (long long)(bn0 + c) * 2048) = v;
      }
    }
  } else {
    // ---------------- prep body: 128x128, BK=64, K=128 ----------------
    const int zz = z - 272;
    const int pz = zz >> 4, px = zz & 15;
    const bf16_t* A;
    const bf16_t* B;
    bf16_t* C;
    int bm0, bn0;
    if (pz < 48) {
      const int h = pz / 3, p = pz - 3 * h;
      A = (p == 2 ? vlT : qkT) + h * 16384;
      B = qkv_wT + (long long)pz * 262144;
      C = Wrot + (long long)pz * 262144;
      bm0 = 0;  bn0 = px * 128;
    } else {
      const int b = pz - 48;
      A = dwT + (long long)b * 262144;
      B = vlT + b * 16384;
      C = tsrT;
      bm0 = px * 128;  bn0 = b * 128;
    }
    bf16_t* shA = smem;          // 8192
    bf16_t* shB = smem + 8192;   // 8192
    const int wm = (w >> 1) * 64;
    const int wn = (w & 1) * 64;
    const int arow0 = (pz < 48 ? 0 : bm0);
    const int brow0 = (pz < 48 ? bn0 : 0);

    f32x4 acc[4][4];
    #pragma unroll
    for (int i = 0; i < 4; ++i)
      #pragma unroll
      for (int j = 0; j < 4; ++j)
        #pragma unroll
        for (int r = 0; r < 4; ++r)
          acc[i][j][r] = 0.0f;

    for (int k0 = 0; k0 < 128; k0 += 64) {
      #pragma unroll
      for (int u = 0; u < 4; ++u) {
        const int seg  = u * 4 + w;
        const int half = seg >> 3;
        const int s8   = seg & 7;
        const int row  = s8 * 16 + r0;
        const int gk   = k0 + half * 32 + c0;
        async16(A + (long long)(arow0 + row) * 128 + gk, &shA[half * 4096 + s8 * 512]);
        async16(B + (long long)(brow0 + row) * 128 + gk, &shB[half * 4096 + s8 * 512]);
      }
      __builtin_amdgcn_s_waitcnt(0);
      __syncthreads();

      const int rc = (kc ^ swr) * 8;
      #pragma unroll
      for (int h = 0; h < 2; ++h) {
        bf16x8 af[4], bfv[4];
        #pragma unroll
        for (int i = 0; i < 4; ++i) {
          af[i]  = *(const bf16x8*)&shA[h * 4096 + (wm + i * 16 + fr) * 32 + rc];
          bfv[i] = *(const bf16x8*)&shB[h * 4096 + (wn + i * 16 + fr) * 32 + rc];
        }
        #pragma unroll
        for (int i = 0; i < 4; ++i)
          #pragma unroll
          for (int j = 0; j < 4; ++j)
            acc[i][j] = __builtin_amdgcn_mfma_f32_16x16x32_bf16(af[i], bfv[j], acc[i][j], 0, 0, 0);
      }
      __syncthreads();
    }

    #pragma unroll
    for (int j = 0; j < 4; ++j) {
      const int col = bn0 + wn + j * 16 + cc;
      #pragma unroll
      for (int i = 0; i < 4; ++i)
        #pragma unroll
        for (int r = 0; r < 4; ++r) {
          const int row = arow0 + wm + i * 16 + rq + r;
          C[(long long)row * 2048 + col] = (bf16_t)acc[i][j][r];
        }
    }
  }
}

// ---------------------------------------------------------------------------
// Flash attention: one block = 64 q-rows x one head, pipelined single-buffer.
// Grid (x=head=16, y=0..31): qt = y<16 ? 31-y : y-16 -> blocks i and i+256
// (same CU under round-robin) always sum to 17 iterations (balanced).
// XCD = (h + 16y) % 8 = h % 8 -> all q-tiles of a head share one XCD L2.
// ---------------------------------------------------------------------------
__device__ __forceinline__ void stage128(const bf16_t* __restrict__ gp, bf16_t* lds,
                                         const long long rstride, const int w, const int l)
{
  #pragma unroll
  for (int s = 0; s < 8; ++s) {
    const int chunk = (w * 8 + s) * 64 + l;
    const int r = chunk >> 4;
    const int c = (chunk & 15) ^ (r & 7);
    async16(gp + (long long)r * rstride + c * 8, &lds[(w * 8 + s) * 512]);
  }
}

__global__ __launch_bounds__(256)
void flash_k(const bf16_t* __restrict__ mixed, const bf16_t* __restrict__ vT,
             bf16_t* __restrict__ ctx, float iscale)
{
  const int h  = blockIdx.x;
  const int y  = blockIdx.y;
  const int qt = (y < 16) ? (31 - y) : (y - 16);   // complementary CU pairing
  const int r0g = qt * 64;
  const int niter = (qt >> 1) + 1;
  const bf16_t* Qp = mixed + h * 384;
  const bf16_t* Kp = mixed + h * 384 + 128;
  const bf16_t* Vp = vT + (long long)h * 262144;

  __shared__ bf16_t sK[16384];   // 128 kv-rows x 128 d, chunk-XOR swizzled
  __shared__ bf16_t sV[16384];   // 128 e-rows  x 128 kv, chunk-XOR swizzled
  __shared__ bf16_t sP[8192];    // 64 q-rows x 128 kv, chunk-XOR swizzled

  const int t  = threadIdx.x;
  const int w  = t >> 6;
  const int l  = t & 63;
  const int fr = l & 15;
  const int kc = l >> 4;
  const int qrow0 = r0g + w * 16;        // this wave's first global q-row

  // Q fragments for the wave's 16 rows: lane holds row fr, k = ks*32 + kc*8
  bf16x8 aq[4];
  #pragma unroll
  for (int ks = 0; ks < 4; ++ks)
    aq[ks] = *(const bf16x8*)(Qp + (long long)(qrow0 + fr) * 6144 + ks * 32 + kc * 8);

  f32x4 oacc[8];
  #pragma unroll
  for (int j = 0; j < 8; ++j)
    #pragma unroll
    for (int r = 0; r < 4; ++r) oacc[j][r] = 0.0f;
  float lsum[4] = {0.f, 0.f, 0.f, 0.f};

  // drain the aq global loads so in-loop vmcnt counts only the async stages
  FK_WAIT0();

  stage128(Kp, sK, 6144, w, l);          // K tile 0
  stage128(Vp, sV, 2048, w, l);          // V tile 0 (cols t0=0)
  FK_WAIT8();                            // K0 landed, V0 (8) in flight
  FK_BAR();

  for (int it = 0; it < niter; ++it) {
    const int t0 = it * 128;

    // ---------------- QK (V(it) loads in flight) ----------------
    f32x4 acc[8];
    #pragma unroll
    for (int j = 0; j < 8; ++j)
      #pragma unroll
      for (int r = 0; r < 4; ++r) acc[j][r] = 0.0f;
    #pragma unroll
    for (int ks = 0; ks < 4; ++ks) {
      bf16x8 bk[8];
      #pragma unroll
      for (int j = 0; j < 8; ++j)
        bk[j] = *(const bf16x8*)&sK[(j * 16 + fr) * 128 + (((ks * 4 + kc) ^ (fr & 7)) * 8)];
      __builtin_amdgcn_s_setprio(1);
      #pragma unroll
      for (int j = 0; j < 8; ++j)
        acc[j] = __builtin_amdgcn_mfma_f32_16x16x32_bf16(aq[ks], bk[j], acc[j], 0, 0, 0);
      __builtin_amdgcn_s_setprio(0);
    }

    // ---------------- softmax (wave-local rows) ----------------
    #pragma unroll
    for (int r = 0; r < 4; ++r) {
      const int q16 = kc * 4 + r;              // row within wave's 16
      const int Rg  = qrow0 + q16;             // global q row
      float rs = 0.f;
      #pragma unroll
      for (int j = 0; j < 8; ++j) {
        const float e = (t0 + j * 16 + fr <= Rg) ? __expf(acc[j][r] * iscale) : 0.0f;
        rs += e;
        sP[(w * 16 + q16) * 128 + (((j * 2 + (fr >> 3)) ^ (q16 & 7)) * 8) + (fr & 7)] = (bf16_t)e;
      }
      rs += __shfl_xor(rs, 1, 64);
      rs += __shfl_xor(rs, 2, 64);
      rs += __shfl_xor(rs, 4, 64);
      rs += __shfl_xor(rs, 8, 64);
      lsum[r] += rs;
    }

    FK_BAR();                              // all waves done reading sK
    if (it + 1 < niter) {
      stage128(Kp + (long long)(t0 + 128) * 6144, sK, 6144, w, l);  // K(t+1) || PV
      FK_WAIT8();                          // V(it) landed (K(t+1) in flight)
    } else {
      FK_WAIT0();                          // V(it) landed
    }
    FK_BAR();                              // V(it) visible to all waves

    // ---------------- PV (K(it+1) loads in flight) ----------------
    #pragma unroll
    for (int ks = 0; ks < 4; ++ks) {
      const bf16x8 ap =
          *(const bf16x8*)&sP[(w * 16 + fr) * 128 + (((ks * 4 + kc) ^ (fr & 7)) * 8)];
      bf16x8 bv[4 + 4];
      #pragma unroll
      for (int j = 0; j < 8; ++j)
        bv[j] = *(const bf16x8*)&sV[(j * 16 + fr) * 128 + (((ks * 4 + kc) ^ (fr & 7)) * 8)];
      __builtin_amdgcn_s_setprio(1);
      #pragma unroll
      for (int j = 0; j < 8; ++j)
        oacc[j] = __builtin_amdgcn_mfma_f32_16x16x32_bf16(ap, bv[j], oacc[j], 0, 0, 0);
      __builtin_amdgcn_s_setprio(0);
    }

    if (it + 1 < niter) {
      FK_BAR();                            // all waves done reading sV
      stage128(Vp + (t0 + 128), sV, 2048, w, l);                    // V(t+1) || next QK
      FK_WAIT8();                          // K(it+1) landed (V(t+1) in flight)
      FK_BAR();                            // K(it+1) visible to all waves
    }
  }

  #pragma unroll
  for (int r = 0; r < 4; ++r) {
    const float inv = 1.0f / lsum[r];
    const int rowg = qrow0 + kc * 4 + r;
    #pragma unroll
    for (int j = 0; j < 8; ++j)
      ctx[(long long)rowg * 2048 + h * 128 + j * 16 + fr] = (bf16_t)(oacc[j][r] * inv);
  }
}

// ---------------------------------------------------------------------------
// front: z-routed mega-kernel, fully parallel (one tile per block).
// ---------------------------------------------------------------------------
__global__ __launch_bounds__(256)
void front_k(const float* __restrict__ hs, bf16_t* __restrict__ hsb,
             const float* __restrict__ svd_tok, bf16_t* __restrict__ stb,
             const float* __restrict__ svd_qk, bf16_t* __restrict__ qkT,
             const float* __restrict__ svd_vl, bf16_t* __restrict__ vlT,
             const float* __restrict__ qkv_w, bf16_t* __restrict__ qkv_wT,
             const float* __restrict__ dense_w, bf16_t* __restrict__ dwT,
             const float* __restrict__ qkv_b, bf16_t* __restrict__ brot)
{
  __shared__ bf16_t sm[32][33];
  const int z = blockIdx.x;
  const int tid = threadIdx.x;

  if (z < 2048) {
    const float* in = (z < 1024) ? hs : svd_tok;
    bf16_t* out = (z < 1024) ? hsb : stb;
    const int base = (z & 1023) * 4096 + tid * 16;
    #pragma unroll
    for (int j = 0; j < 4; ++j) {
      const f32x4 v = *(const f32x4*)(in + base + j * 4);
      bf16x4 o;
      #pragma unroll
      for (int k = 0; k < 4; ++k) o[k] = (bf16_t)v[k];
      *(bf16x4*)(out + base + j * 4) = o;
    }
  } else if (z < 2560) {
    const int zz = z - 2048;
    const int zr = zz >> 4;                 // 0..31
    const int tile = zz & 15;
    const float* ip = (zr < 16 ? svd_qk : svd_vl) + (long long)(zr & 15) * 16384;
    bf16_t* op = (zr < 16 ? qkT : vlT) + (long long)(zr & 15) * 16384;
    const int r0 = (tile & 3) << 5;
    const int c0 = (tile >> 2) << 5;
    const int tx = tid & 31;
    const int ty = tid >> 5;
    #pragma unroll
    for (int yy = ty; yy < 32; yy += 8)
      sm[yy][tx] = (bf16_t)ip[(long long)(r0 + yy) * 128 + c0 + tx];
    __syncthreads();
    #pragma unroll
    for (int yy = ty; yy < 32; yy += 8)
      op[(long long)(c0 + yy) * 128 + r0 + tx] = sm[tx][yy];
  } else if (z < 18944) {
    const int zz = z - 2560;
    const int zb = zz >> 8;                 // batch 0..63
    const int tile = zz & 255;              // 4 r-tiles x 64 c-tiles
    const float* ip = (zb < 48) ? qkv_w + (long long)zb * 262144
                                : dense_w + (long long)(zb - 48) * 262144;
    bf16_t* op = (zb < 48) ? qkv_wT + (long long)zb * 262144
                           : dwT + (long long)(zb - 48) * 262144;
    const int r0 = (tile & 3) << 5;
    const int c0 = (tile >> 2) << 5;
    const int tx = tid & 31;
    const int ty = tid >> 5;
    #pragma unroll
    for (int yy = ty; yy < 32; yy += 8)
      sm[yy][tx] = (bf16_t)ip[(long long)(r0 + yy) * 2048 + c0 + tx];
    __syncthreads();
    #pragma unroll
    for (int yy = ty; yy < 32; yy += 8)
      op[(long long)(c0 + yy) * 128 + r0 + tx] = sm[tx][yy];
  } else {
    const int hp = (z - 18944) * 2 + (tid >> 7);   // 0..47
    const int h = hp / 3, p = hp % 3;
    const int e = tid & 127;
    const float* R = (p == 2 ? (const float*)svd_vl : (const float*)svd_qk) + (long long)h * 16384;
    const float* b = qkv_b + h * 384 + p * 128;
    float acc = 0.f;
    for (int d = 0; d < 128; ++d)
      acc += b[d] * R[d * 128 + e];
    brot[h * 384 + p * 128 + e] = (bf16_t)acc;
  }
}

extern "C" void kernel_launch(void* const* d_in, const int* in_sizes, int n_in,
                              void* d_out, int out_size, void* d_ws, size_t ws_size,
                              hipStream_t stream)
{
  const float* hs      = (const float*)d_in[0];
  const float* qkv_w   = (const float*)d_in[2];
  const float* qkv_b   = (const float*)d_in[3];
  const float* svd_tok = (const float*)d_in[4];
  const float* svd_qk  = (const float*)d_in[5];
  const float* svd_vl  = (const float*)d_in[6];
  const float* dense_w = (const float*)d_in[7];
  const float* dense_b = (const float*)d_in[8];
  float* out = (float*)d_out;
  bf16_t* ws = (bf16_t*)d_ws;

  bf16_t* hsb    = ws;                    //  4,194,304
  bf16_t* stb    = ws +  4194304LL;       //  4,194,304
  bf16_t* Mbuf   = ws +  8388608LL;       //  4,194,304
  bf16_t* x2     = ws + 12582912LL;       //  4,194,304
  bf16_t* qkv_wT = ws + 16777216LL;       // 12,582,912
  bf16_t* Wrot   = ws + 29360128LL;       // 12,582,912
  bf16_t* mixed  = ws + 41943040LL;       // 12,582,912
  bf16_t* vT     = ws + 54525952LL;       //  4,194,304
  bf16_t* ctx    = ws + 58720256LL;       //  4,194,304
  bf16_t* dwT    = ws + 62914560LL;       //  4,194,304
  bf16_t* tsrT   = ws + 67108864LL;       //  4,194,304
  bf16_t* qkT    = ws + 71303168LL;       //    262,144
  bf16_t* vlT    = ws + 71565312LL;       //    262,144
  bf16_t* brot   = ws + 71827456LL;       //      6,144
  if (ws_size < 71833600ULL * 2ULL) return;

  const float iscale = 0.08838834764831845f;   // 1/sqrt(128)

  // all memory-bound prep in one launch (one tile per block, no serial tail)
  front_k<<<dim3(18968), 256, 0, stream>>>(hs, hsb, svd_tok, stb,
      svd_qk, qkT, svd_vl, vlT, qkv_w, qkv_wT, dense_w, dwT, qkv_b, brot);
  // M GEMM (272 symmetric blocks, heavy-first) + Wrot/tsrT prep in one launch
  gemm_mprep<<<dim3(1296), 256, 0, stream>>>(qkT, vlT, qkv_wT, dwT,
      Wrot, tsrT, stb, Mbuf);
  // x2 = hs @ M  (M symmetric -> NT ok), BK=128
  gemm_nt64k<<<dim3(16, 32), 256, 0, stream>>>(hsb, Mbuf, x2, nullptr,
      2048, 2048, 2048, 2048, 1.0f, 0);
  // mixed = x2 @ Wrot^T + brot  (128^2 tile, BK=64); V blocks also emit vT
  gemm_nt128<<<dim3(48, 16), 256, 0, stream>>>(x2, Wrot, mixed, brot, vT,
      2048, 2048, 2048, 6144, 1.0f, 8 | 16);
  // fused attention -> ctx (balanced pairing + pipelined loads)
  flash_k<<<dim3(16, 32), 256, 0, stream>>>(mixed, vT, ctx, iscale);
  // out = ctx @ tsrT^T + dense_b  (f32 store), BK=128
  gemm_nt64k<<<dim3(16, 32), 256, 0, stream>>>(ctx, tsrT, out, dense_b,
      2048, 2048, 2048, 2048, 1.0f, 4);
}

// Round 6
// 360.554 us; speedup vs baseline: 1.0644x; 1.0545x over previous
//
#include <hip/hip_runtime.h>
#include <hip/hip_bf16.h>
#include <stdint.h>
#include <math.h>

// ---------------------------------------------------------------------------
// Attention_74852690035363 — f32 I/O, bf16 MFMA compute.
//   front = casts + all weight transposes + brot  [ONE z-routed launch]
//   Mprep = M GEMM (272 blk, symmetric upper-triangle only + mirrored write)
//           + Wrot/tsrT prep (1024 blk)  [ONE launch, heavy blocks first]
//   x2    = hs·M (M symmetric)          [64x128 tile, BK=128, XCD col-chunk]
//   mixed = x2·Wrotᵀ + brot             [128² tile BK=64, 768 blk, XCD col-chunk]
//   vT    = transpose of V blocks of mixed  [restored — R4/R5 fusion REVERTED:
//           fused vT stream evicted Wrot from L2 (+14MB FETCH, 66->91µs)]
//   flash = fused exp(scale·q·kᵀ) causal / rowsum / P·V -> ctx
//   out   = ctx·tsrTᵀ + dense_b         [64x128 tile, BK=128, XCD col-chunk]
// XCD col-chunk swizzle (T1): xcd = linear%8 owns col-tiles [xcd*cpx,+cpx) ×
// all rows -> per-XCD B-panel (3MB mixed / 1MB x2,out) is L2-resident; A
// re-reads absorbed by L3. Bijective since nwg%8==0 (768, 512).
// LDS tiles 16B-chunk XOR-swizzled.
// ---------------------------------------------------------------------------

typedef __bf16 bf16_t;
typedef __bf16 bf16x8 __attribute__((ext_vector_type(8)));
typedef __bf16 bf16x4 __attribute__((ext_vector_type(4)));
typedef float  f32x4  __attribute__((ext_vector_type(4)));

__device__ __forceinline__ void async16(const void* g, void* l) {
  __builtin_amdgcn_global_load_lds(
      (const __attribute__((address_space(1))) void*)(uintptr_t)g,
      (__attribute__((address_space(3))) void*)(uint32_t)(uintptr_t)l,
      16, 0, 0);
}

#define FK_WAIT8() do { asm volatile("s_waitcnt vmcnt(8)" ::: "memory"); \
                        __builtin_amdgcn_sched_barrier(0); } while (0)
#define FK_WAIT0() do { asm volatile("s_waitcnt vmcnt(0)" ::: "memory"); \
                        __builtin_amdgcn_sched_barrier(0); } while (0)
#define FK_BAR()   do { __builtin_amdgcn_s_barrier(); \
                        __builtin_amdgcn_sched_barrier(0); } while (0)

// XCD column-chunked block decode: each XCD owns a contiguous band of
// column-tiles across ALL row-tiles -> B-panel L2-resident per XCD.
__device__ __forceinline__ void xcd_cols(int& bx, int& by) {
  const int nbx = (int)gridDim.x;
  const int lin = (int)blockIdx.x + nbx * (int)blockIdx.y;
  const int xcd = lin & 7;
  const int idx = lin >> 3;
  const int cpx = nbx >> 3;
  bx = xcd * cpx + idx % cpx;
  by = idx / cpx;
}

// ---------------- 128x128-tile NT GEMM, BK=64 (for `mixed`) ----------------
// flags&8: bf16 bias
__global__ __launch_bounds__(256)
void gemm_nt128(const bf16_t* __restrict__ A, const bf16_t* __restrict__ B,
                void* __restrict__ Cv, const void* __restrict__ biasv,
                int K, int lda, int ldb, int ldc, float alpha, int flags)
{
  int bxs, bys;
  xcd_cols(bxs, bys);
  const int bm0 = bys * 128;
  const int bn0 = bxs * 128;

  __shared__ bf16_t shA[8192];   // 2 halves x 128x32
  __shared__ bf16_t shB[8192];

  const int t  = threadIdx.x;
  const int w  = t >> 6;
  const int l  = t & 63;
  const int wm = (w >> 1) * 64;
  const int wn = (w & 1) * 64;
  const int r0 = l >> 2;
  const int c0 = ((l & 3) ^ ((l >> 3) & 3)) * 8;
  const int fr = l & 15;
  const int kc = l >> 4;
  const int swr = ((fr >> 1) & 3);

  f32x4 acc[4][4];
  #pragma unroll
  for (int i = 0; i < 4; ++i)
    #pragma unroll
    for (int j = 0; j < 4; ++j)
      #pragma unroll
      for (int r = 0; r < 4; ++r)
        acc[i][j][r] = 0.0f;

  for (int k0 = 0; k0 < K; k0 += 64) {
    #pragma unroll
    for (int u = 0; u < 4; ++u) {
      const int seg  = u * 4 + w;
      const int half = seg >> 3;
      const int s8   = seg & 7;
      const int row  = s8 * 16 + r0;
      const int gk   = k0 + half * 32 + c0;
      async16(A + (long long)(bm0 + row) * lda + gk, &shA[half * 4096 + s8 * 512]);
      async16(B + (long long)(bn0 + row) * ldb + gk, &shB[half * 4096 + s8 * 512]);
    }
    __builtin_amdgcn_s_waitcnt(0);
    __syncthreads();

    const int rc = (kc ^ swr) * 8;
    #pragma unroll
    for (int h = 0; h < 2; ++h) {
      bf16x8 af[4], bfv[4];
      #pragma unroll
      for (int i = 0; i < 4; ++i) {
        af[i]  = *(const bf16x8*)&shA[h * 4096 + (wm + i * 16 + fr) * 32 + rc];
        bfv[i] = *(const bf16x8*)&shB[h * 4096 + (wn + i * 16 + fr) * 32 + rc];
      }
      #pragma unroll
      for (int i = 0; i < 4; ++i)
        #pragma unroll
        for (int j = 0; j < 4; ++j)
          acc[i][j] = __builtin_amdgcn_mfma_f32_16x16x32_bf16(af[i], bfv[j], acc[i][j], 0, 0, 0);
    }
    __syncthreads();
  }

  const int cc = l & 15;
  const int rq = (l >> 4) * 4;
  bf16_t* C = (bf16_t*)Cv;
  const bf16_t* bias = (flags & 8) ? (const bf16_t*)biasv : nullptr;
  #pragma unroll
  for (int j = 0; j < 4; ++j) {
    const int col = bn0 + wn + j * 16 + cc;
    const float bv = bias ? (float)bias[col] : 0.0f;
    #pragma unroll
    for (int i = 0; i < 4; ++i)
      #pragma unroll
      for (int r = 0; r < 4; ++r) {
        const int row = bm0 + wm + i * 16 + rq + r;
        C[(long long)row * ldc + col] = (bf16_t)(acc[i][j][r] * alpha + bv);
      }
  }
}

// ---------------- 64x128-tile NT GEMM, BK=128 (x2 / out) -------------------
// flags&4: f32 C + f32 bias
__global__ __launch_bounds__(256)
void gemm_nt64k(const bf16_t* __restrict__ A, const bf16_t* __restrict__ B,
                void* __restrict__ Cv, const void* __restrict__ biasv,
                int K, int lda, int ldb, int ldc, float alpha, int flags)
{
  int bxs, bys;
  xcd_cols(bxs, bys);
  const int bm0 = bys * 64;
  const int bn0 = bxs * 128;

  __shared__ bf16_t shA[8192];    // 4 quarters x 64x32   (16 KB)
  __shared__ bf16_t shB[16384];   // 4 quarters x 128x32  (32 KB)

  const int t  = threadIdx.x;
  const int w  = t >> 6;
  const int l  = t & 63;
  const int wm = (w >> 1) * 32;
  const int wn = (w & 1) * 64;
  const int r0 = l >> 2;
  const int c0 = ((l & 3) ^ ((l >> 3) & 3)) * 8;
  const int fr = l & 15;
  const int kc = l >> 4;
  const int swr = ((fr >> 1) & 3);

  f32x4 acc[2][4];
  #pragma unroll
  for (int i = 0; i < 2; ++i)
    #pragma unroll
    for (int j = 0; j < 4; ++j)
      #pragma unroll
      for (int r = 0; r < 4; ++r)
        acc[i][j][r] = 0.0f;

  for (int k0 = 0; k0 < K; k0 += 128) {
    #pragma unroll
    for (int u = 0; u < 4; ++u) {          // A: 16 segs (4 quarters x 4)
      const int seg = u * 4 + w;
      const int q   = seg >> 2;
      const int s4  = seg & 3;
      async16(A + (long long)(bm0 + s4 * 16 + r0) * lda + (k0 + q * 32 + c0),
              &shA[q * 2048 + s4 * 512]);
    }
    #pragma unroll
    for (int u = 0; u < 8; ++u) {          // B: 32 segs (4 quarters x 8)
      const int seg = u * 4 + w;
      const int q   = seg >> 3;
      const int s8  = seg & 7;
      async16(B + (long long)(bn0 + s8 * 16 + r0) * ldb + (k0 + q * 32 + c0),
              &shB[q * 4096 + s8 * 512]);
    }
    __builtin_amdgcn_s_waitcnt(0);
    __syncthreads();

    const int rc = (kc ^ swr) * 8;
    #pragma unroll
    for (int q = 0; q < 4; ++q) {
      bf16x8 af[2], bfv[4];
      #pragma unroll
      for (int i = 0; i < 2; ++i)
        af[i]  = *(const bf16x8*)&shA[q * 2048 + (wm + i * 16 + fr) * 32 + rc];
      #pragma unroll
      for (int j = 0; j < 4; ++j)
        bfv[j] = *(const bf16x8*)&shB[q * 4096 + (wn + j * 16 + fr) * 32 + rc];
      #pragma unroll
      for (int i = 0; i < 2; ++i)
        #pragma unroll
        for (int j = 0; j < 4; ++j)
          acc[i][j] = __builtin_amdgcn_mfma_f32_16x16x32_bf16(af[i], bfv[j], acc[i][j], 0, 0, 0);
    }
    __syncthreads();
  }

  const int cc = l & 15;
  const int rq = (l >> 4) * 4;
  if (flags & 4) {
    float* C = (float*)Cv;
    const float* bias = (const float*)biasv;
    #pragma unroll
    for (int j = 0; j < 4; ++j) {
      const int col = bn0 + wn + j * 16 + cc;
      const float bv = bias ? bias[col] : 0.0f;
      #pragma unroll
      for (int i = 0; i < 2; ++i)
        #pragma unroll
        for (int r = 0; r < 4; ++r) {
          const int row = bm0 + wm + i * 16 + rq + r;
          C[(long long)row * ldc + col] = acc[i][j][r] * alpha + bv;
        }
    }
  } else {
    bf16_t* C = (bf16_t*)Cv;
    #pragma unroll
    for (int j = 0; j < 4; ++j) {
      const int col = bn0 + wn + j * 16 + cc;
      #pragma unroll
      for (int i = 0; i < 2; ++i)
        #pragma unroll
        for (int r = 0; r < 4; ++r) {
          const int row = bm0 + wm + i * 16 + rq + r;
          C[(long long)row * ldc + col] = (bf16_t)(acc[i][j][r] * alpha);
        }
    }
  }
}

// ---------------- merged M GEMM + prep GEMMs (one launch) ------------------
// z < 272: M super-tile blocks (symmetric: only J>=I computed; off-diagonal
//          blocks mirror their 64x128 tile via transposed-LDS bounce,
//          coalesced bf16x8 global writes — bitwise equal to recompute).
// z >= 272: Wrot/tsrT prep (128x128, K=128), as before.
__global__ __launch_bounds__(256)
void gemm_mprep(const bf16_t* __restrict__ qkT, const bf16_t* __restrict__ vlT,
                const bf16_t* __restrict__ qkv_wT, const bf16_t* __restrict__ dwT,
                bf16_t* __restrict__ Wrot, bf16_t* __restrict__ tsrT,
                const bf16_t* __restrict__ stb, bf16_t* __restrict__ Mbuf)
{
  __shared__ bf16_t smem[16384];   // 32 KB, carved per branch
  const int z = blockIdx.x;
  const int t  = threadIdx.x;
  const int w  = t >> 6;
  const int l  = t & 63;
  const int r0 = l >> 2;
  const int c0 = ((l & 3) ^ ((l >> 3) & 3)) * 8;
  const int fr = l & 15;
  const int kc = l >> 4;
  const int swr = ((fr >> 1) & 3);
  const int cc = l & 15;
  const int rq = (l >> 4) * 4;

  if (z < 272) {
    // ------- M body: 64x128 tile, BK=64, K=2048, stb·stbᵀ, upper-tri -------
    int sup = z >> 1;
    const int h2 = z & 1;
    int I = 0;
    #pragma unroll 1
    while (sup >= 16 - I) { sup -= 16 - I; ++I; }
    const int J = I + sup;                 // J >= I
    const int bm0 = I * 128 + h2 * 64;
    const int bn0 = J * 128;
    bf16_t* shA = smem;          // 4096
    bf16_t* shB = smem + 4096;   // 8192
    const int wm = (w >> 1) * 32;
    const int wn = (w & 1) * 64;

    f32x4 acc[2][4];
    #pragma unroll
    for (int i = 0; i < 2; ++i)
      #pragma unroll
      for (int j = 0; j < 4; ++j)
        #pragma unroll
        for (int r = 0; r < 4; ++r)
          acc[i][j][r] = 0.0f;

    for (int k0 = 0; k0 < 2048; k0 += 64) {
      #pragma unroll
      for (int u = 0; u < 2; ++u) {
        const int seg  = u * 4 + w;
        const int half = seg >> 2;
        const int s4   = seg & 3;
        async16(stb + (long long)(bm0 + s4 * 16 + r0) * 2048 + (k0 + half * 32 + c0),
                &shA[half * 2048 + s4 * 512]);
      }
      #pragma unroll
      for (int u = 0; u < 4; ++u) {
        const int seg  = u * 4 + w;
        const int half = seg >> 3;
        const int s8   = seg & 7;
        async16(stb + (long long)(bn0 + s8 * 16 + r0) * 2048 + (k0 + half * 32 + c0),
                &shB[half * 4096 + s8 * 512]);
      }
      __builtin_amdgcn_s_waitcnt(0);
      __syncthreads();

      const int rc = (kc ^ swr) * 8;
      #pragma unroll
      for (int h = 0; h < 2; ++h) {
        bf16x8 af[2], bfv[4];
        #pragma unroll
        for (int i = 0; i < 2; ++i)
          af[i]  = *(const bf16x8*)&shA[h * 2048 + (wm + i * 16 + fr) * 32 + rc];
        #pragma unroll
        for (int j = 0; j < 4; ++j)
          bfv[j] = *(const bf16x8*)&shB[h * 4096 + (wn + j * 16 + fr) * 32 + rc];
        #pragma unroll
        for (int i = 0; i < 2; ++i)
          #pragma unroll
          for (int j = 0; j < 4; ++j)
            acc[i][j] = __builtin_amdgcn_mfma_f32_16x16x32_bf16(af[i], bfv[j], acc[i][j], 0, 0, 0);
      }
      __syncthreads();
    }

    const bool mir = (I != J);
    #pragma unroll
    for (int j = 0; j < 4; ++j) {
      const int coll = wn + j * 16 + cc;
      #pragma unroll
      for (int i = 0; i < 2; ++i)
        #pragma unroll
        for (int r = 0; r < 4; ++r) {
          const int rowl = wm + i * 16 + rq + r;
          const bf16_t v = (bf16_t)acc[i][j][r];
          Mbuf[(long long)(bm0 + rowl) * 2048 + bn0 + coll] = v;
          if (mir)   // transposed store: 64-elem rows, chunk-XOR
            smem[coll * 64 + (((rowl >> 3) ^ (coll & 7)) * 8) + (rowl & 7)] = v;
        }
    }
    if (mir) {
      __syncthreads();
      // coalesced mirror write: 8 lanes x 16B cover one 128B row of M^T tile
      const int cr  = t >> 3;              // row within pass (0..31)
      const int mc8 = t & 7;               // 16B chunk within row
      bf16_t* mp = Mbuf + bm0 + mc8 * 8;
      #pragma unroll
      for (int p = 0; p < 4; ++p) {
        const int c = p * 32 + cr;         // 0..127 (col of orig = row of mirror)
        const bf16x8 v = *(const bf16x8*)&smem[c * 64 + ((mc8 ^ (c & 7)) * 8)];
        *(bf16x8*)(mp + (long long)(bn0 + c) * 2048) = v;
      }
    }
  } else {
    // ---------------- prep body: 128x128, BK=64, K=128 ----------------
    const int zz = z - 272;
    const int pz = zz >> 4, px = zz & 15;
    const bf16_t* A;
    const bf16_t* B;
    bf16_t* C;
    int bm0, bn0;
    if (pz < 48) {
      const int h = pz / 3, p = pz - 3 * h;
      A = (p == 2 ? vlT : qkT) + h * 16384;
      B = qkv_wT + (long long)pz * 262144;
      C = Wrot + (long long)pz * 262144;
      bm0 = 0;  bn0 = px * 128;
    } else {
      const int b = pz - 48;
      A = dwT + (long long)b * 262144;
      B = vlT + b * 16384;
      C = tsrT;
      bm0 = px * 128;  bn0 = b * 128;
    }
    bf16_t* shA = smem;          // 8192
    bf16_t* shB = smem + 8192;   // 8192
    const int wm = (w >> 1) * 64;
    const int wn = (w & 1) * 64;
    const int arow0 = (pz < 48 ? 0 : bm0);
    const int brow0 = (pz < 48 ? bn0 : 0);

    f32x4 acc[4][4];
    #pragma unroll
    for (int i = 0; i < 4; ++i)
      #pragma unroll
      for (int j = 0; j < 4; ++j)
        #pragma unroll
        for (int r = 0; r < 4; ++r)
          acc[i][j][r] = 0.0f;

    for (int k0 = 0; k0 < 128; k0 += 64) {
      #pragma unroll
      for (int u = 0; u < 4; ++u) {
        const int seg  = u * 4 + w;
        const int half = seg >> 3;
        const int s8   = seg & 7;
        const int row  = s8 * 16 + r0;
        const int gk   = k0 + half * 32 + c0;
        async16(A + (long long)(arow0 + row) * 128 + gk, &shA[half * 4096 + s8 * 512]);
        async16(B + (long long)(brow0 + row) * 128 + gk, &shB[half * 4096 + s8 * 512]);
      }
      __builtin_amdgcn_s_waitcnt(0);
      __syncthreads();

      const int rc = (kc ^ swr) * 8;
      #pragma unroll
      for (int h = 0; h < 2; ++h) {
        bf16x8 af[4], bfv[4];
        #pragma unroll
        for (int i = 0; i < 4; ++i) {
          af[i]  = *(const bf16x8*)&shA[h * 4096 + (wm + i * 16 + fr) * 32 + rc];
          bfv[i] = *(const bf16x8*)&shB[h * 4096 + (wn + i * 16 + fr) * 32 + rc];
        }
        #pragma unroll
        for (int i = 0; i < 4; ++i)
          #pragma unroll
          for (int j = 0; j < 4; ++j)
            acc[i][j] = __builtin_amdgcn_mfma_f32_16x16x32_bf16(af[i], bfv[j], acc[i][j], 0, 0, 0);
      }
      __syncthreads();
    }

    #pragma unroll
    for (int j = 0; j < 4; ++j) {
      const int col = bn0 + wn + j * 16 + cc;
      #pragma unroll
      for (int i = 0; i < 4; ++i)
        #pragma unroll
        for (int r = 0; r < 4; ++r) {
          const int row = arow0 + wm + i * 16 + rq + r;
          C[(long long)row * 2048 + col] = (bf16_t)acc[i][j][r];
        }
    }
  }
}

// ---------------------------------------------------------------------------
// Flash attention: one block = 64 q-rows x one head, pipelined single-buffer.
// Grid (x=head=16, y=0..31): qt = y<16 ? 31-y : y-16 -> blocks i and i+256
// (same CU under round-robin) always sum to 17 iterations (balanced).
// XCD = (h + 16y) % 8 = h % 8 -> all q-tiles of a head share one XCD L2.
// ---------------------------------------------------------------------------
__device__ __forceinline__ void stage128(const bf16_t* __restrict__ gp, bf16_t* lds,
                                         const long long rstride, const int w, const int l)
{
  #pragma unroll
  for (int s = 0; s < 8; ++s) {
    const int chunk = (w * 8 + s) * 64 + l;
    const int r = chunk >> 4;
    const int c = (chunk & 15) ^ (r & 7);
    async16(gp + (long long)r * rstride + c * 8, &lds[(w * 8 + s) * 512]);
  }
}

__global__ __launch_bounds__(256)
void flash_k(const bf16_t* __restrict__ mixed, const bf16_t* __restrict__ vT,
             bf16_t* __restrict__ ctx, float iscale)
{
  const int h  = blockIdx.x;
  const int y  = blockIdx.y;
  const int qt = (y < 16) ? (31 - y) : (y - 16);   // complementary CU pairing
  const int r0g = qt * 64;
  const int niter = (qt >> 1) + 1;
  const bf16_t* Qp = mixed + h * 384;
  const bf16_t* Kp = mixed + h * 384 + 128;
  const bf16_t* Vp = vT + (long long)h * 262144;

  __shared__ bf16_t sK[16384];   // 128 kv-rows x 128 d, chunk-XOR swizzled
  __shared__ bf16_t sV[16384];   // 128 e-rows  x 128 kv, chunk-XOR swizzled
  __shared__ bf16_t sP[8192];    // 64 q-rows x 128 kv, chunk-XOR swizzled

  const int t  = threadIdx.x;
  const int w  = t >> 6;
  const int l  = t & 63;
  const int fr = l & 15;
  const int kc = l >> 4;
  const int qrow0 = r0g + w * 16;        // this wave's first global q-row

  // Q fragments for the wave's 16 rows: lane holds row fr, k = ks*32 + kc*8
  bf16x8 aq[4];
  #pragma unroll
  for (int ks = 0; ks < 4; ++ks)
    aq[ks] = *(const bf16x8*)(Qp + (long long)(qrow0 + fr) * 6144 + ks * 32 + kc * 8);

  f32x4 oacc[8];
  #pragma unroll
  for (int j = 0; j < 8; ++j)
    #pragma unroll
    for (int r = 0; r < 4; ++r) oacc[j][r] = 0.0f;
  float lsum[4] = {0.f, 0.f, 0.f, 0.f};

  // drain the aq global loads so in-loop vmcnt counts only the async stages
  FK_WAIT0();

  stage128(Kp, sK, 6144, w, l);          // K tile 0
  stage128(Vp, sV, 2048, w, l);          // V tile 0 (cols t0=0)
  FK_WAIT8();                            // K0 landed, V0 (8) in flight
  FK_BAR();

  for (int it = 0; it < niter; ++it) {
    const int t0 = it * 128;

    // ---------------- QK (V(it) loads in flight) ----------------
    f32x4 acc[8];
    #pragma unroll
    for (int j = 0; j < 8; ++j)
      #pragma unroll
      for (int r = 0; r < 4; ++r) acc[j][r] = 0.0f;
    #pragma unroll
    for (int ks = 0; ks < 4; ++ks) {
      bf16x8 bk[8];
      #pragma unroll
      for (int j = 0; j < 8; ++j)
        bk[j] = *(const bf16x8*)&sK[(j * 16 + fr) * 128 + (((ks * 4 + kc) ^ (fr & 7)) * 8)];
      __builtin_amdgcn_s_setprio(1);
      #pragma unroll
      for (int j = 0; j < 8; ++j)
        acc[j] = __builtin_amdgcn_mfma_f32_16x16x32_bf16(aq[ks], bk[j], acc[j], 0, 0, 0);
      __builtin_amdgcn_s_setprio(0);
    }

    // ---------------- softmax (wave-local rows) ----------------
    #pragma unroll
    for (int r = 0; r < 4; ++r) {
      const int q16 = kc * 4 + r;              // row within wave's 16
      const int Rg  = qrow0 + q16;             // global q row
      float rs = 0.f;
      #pragma unroll
      for (int j = 0; j < 8; ++j) {
        const float e = (t0 + j * 16 + fr <= Rg) ? __expf(acc[j][r] * iscale) : 0.0f;
        rs += e;
        sP[(w * 16 + q16) * 128 + (((j * 2 + (fr >> 3)) ^ (q16 & 7)) * 8) + (fr & 7)] = (bf16_t)e;
      }
      rs += __shfl_xor(rs, 1, 64);
      rs += __shfl_xor(rs, 2, 64);
      rs += __shfl_xor(rs, 4, 64);
      rs += __shfl_xor(rs, 8, 64);
      lsum[r] += rs;
    }

    FK_BAR();                              // all waves done reading sK
    if (it + 1 < niter) {
      stage128(Kp + (long long)(t0 + 128) * 6144, sK, 6144, w, l);  // K(t+1) || PV
      FK_WAIT8();                          // V(it) landed (K(t+1) in flight)
    } else {
      FK_WAIT0();                          // V(it) landed
    }
    FK_BAR();                              // V(it) visible to all waves

    // ---------------- PV (K(it+1) loads in flight) ----------------
    #pragma unroll
    for (int ks = 0; ks < 4; ++ks) {
      const bf16x8 ap =
          *(const bf16x8*)&sP[(w * 16 + fr) * 128 + (((ks * 4 + kc) ^ (fr & 7)) * 8)];
      bf16x8 bv[8];
      #pragma unroll
      for (int j = 0; j < 8; ++j)
        bv[j] = *(const bf16x8*)&sV[(j * 16 + fr) * 128 + (((ks * 4 + kc) ^ (fr & 7)) * 8)];
      __builtin_amdgcn_s_setprio(1);
      #pragma unroll
      for (int j = 0; j < 8; ++j)
        oacc[j] = __builtin_amdgcn_mfma_f32_16x16x32_bf16(ap, bv[j], oacc[j], 0, 0, 0);
      __builtin_amdgcn_s_setprio(0);
    }

    if (it + 1 < niter) {
      FK_BAR();                            // all waves done reading sV
      stage128(Vp + (t0 + 128), sV, 2048, w, l);                    // V(t+1) || next QK
      FK_WAIT8();                          // K(it+1) landed (V(t+1) in flight)
      FK_BAR();                            // K(it+1) visible to all waves
    }
  }

  #pragma unroll
  for (int r = 0; r < 4; ++r) {
    const float inv = 1.0f / lsum[r];
    const int rowg = qrow0 + kc * 4 + r;
    #pragma unroll
    for (int j = 0; j < 8; ++j)
      ctx[(long long)rowg * 2048 + h * 128 + j * 16 + fr] = (bf16_t)(oacc[j][r] * inv);
  }
}

// ---------------------------------------------------------------------------
// front: z-routed mega-kernel, fully parallel (one tile per block).
// ---------------------------------------------------------------------------
__global__ __launch_bounds__(256)
void front_k(const float* __restrict__ hs, bf16_t* __restrict__ hsb,
             const float* __restrict__ svd_tok, bf16_t* __restrict__ stb,
             const float* __restrict__ svd_qk, bf16_t* __restrict__ qkT,
             const float* __restrict__ svd_vl, bf16_t* __restrict__ vlT,
             const float* __restrict__ qkv_w, bf16_t* __restrict__ qkv_wT,
             const float* __restrict__ dense_w, bf16_t* __restrict__ dwT,
             const float* __restrict__ qkv_b, bf16_t* __restrict__ brot)
{
  __shared__ bf16_t sm[32][33];
  const int z = blockIdx.x;
  const int tid = threadIdx.x;

  if (z < 2048) {
    const float* in = (z < 1024) ? hs : svd_tok;
    bf16_t* out = (z < 1024) ? hsb : stb;
    const int base = (z & 1023) * 4096 + tid * 16;
    #pragma unroll
    for (int j = 0; j < 4; ++j) {
      const f32x4 v = *(const f32x4*)(in + base + j * 4);
      bf16x4 o;
      #pragma unroll
      for (int k = 0; k < 4; ++k) o[k] = (bf16_t)v[k];
      *(bf16x4*)(out + base + j * 4) = o;
    }
  } else if (z < 2560) {
    const int zz = z - 2048;
    const int zr = zz >> 4;                 // 0..31
    const int tile = zz & 15;
    const float* ip = (zr < 16 ? svd_qk : svd_vl) + (long long)(zr & 15) * 16384;
    bf16_t* op = (zr < 16 ? qkT : vlT) + (long long)(zr & 15) * 16384;
    const int r0 = (tile & 3) << 5;
    const int c0 = (tile >> 2) << 5;
    const int tx = tid & 31;
    const int ty = tid >> 5;
    #pragma unroll
    for (int yy = ty; yy < 32; yy += 8)
      sm[yy][tx] = (bf16_t)ip[(long long)(r0 + yy) * 128 + c0 + tx];
    __syncthreads();
    #pragma unroll
    for (int yy = ty; yy < 32; yy += 8)
      op[(long long)(c0 + yy) * 128 + r0 + tx] = sm[tx][yy];
  } else if (z < 18944) {
    const int zz = z - 2560;
    const int zb = zz >> 8;                 // batch 0..63
    const int tile = zz & 255;              // 4 r-tiles x 64 c-tiles
    const float* ip = (zb < 48) ? qkv_w + (long long)zb * 262144
                                : dense_w + (long long)(zb - 48) * 262144;
    bf16_t* op = (zb < 48) ? qkv_wT + (long long)zb * 262144
                           : dwT + (long long)(zb - 48) * 262144;
    const int r0 = (tile & 3) << 5;
    const int c0 = (tile >> 2) << 5;
    const int tx = tid & 31;
    const int ty = tid >> 5;
    #pragma unroll
    for (int yy = ty; yy < 32; yy += 8)
      sm[yy][tx] = (bf16_t)ip[(long long)(r0 + yy) * 2048 + c0 + tx];
    __syncthreads();
    #pragma unroll
    for (int yy = ty; yy < 32; yy += 8)
      op[(long long)(c0 + yy) * 128 + r0 + tx] = sm[tx][yy];
  } else {
    const int hp = (z - 18944) * 2 + (tid >> 7);   // 0..47
    const int h = hp / 3, p = hp % 3;
    const int e = tid & 127;
    const float* R = (p == 2 ? (const float*)svd_vl : (const float*)svd_qk) + (long long)h * 16384;
    const float* b = qkv_b + h * 384 + p * 128;
    float acc = 0.f;
    for (int d = 0; d < 128; ++d)
      acc += b[d] * R[d * 128 + e];
    brot[h * 384 + p * 128 + e] = (bf16_t)acc;
  }
}

// bf16 -> bf16 transpose (coalesced both sides via LDS tile)
__global__ __launch_bounds__(256)
void transpose_b2b(const bf16_t* __restrict__ in, bf16_t* __restrict__ out,
                   int R, long long zsi, int rsi, long long zso)
{
  __shared__ bf16_t sm[32][33];
  const int z  = blockIdx.z;
  const int r0 = blockIdx.x << 5;
  const int c0 = blockIdx.y << 5;
  const int tx = threadIdx.x & 31;
  const int ty = threadIdx.x >> 5;
  const bf16_t* ip = in + (long long)z * zsi;
  bf16_t* op = out + (long long)z * zso;
  #pragma unroll
  for (int yy = ty; yy < 32; yy += 8)
    sm[yy][tx] = ip[(long long)(r0 + yy) * rsi + c0 + tx];
  __syncthreads();
  #pragma unroll
  for (int yy = ty; yy < 32; yy += 8)
    op[(long long)(c0 + yy) * R + r0 + tx] = sm[tx][yy];
}

extern "C" void kernel_launch(void* const* d_in, const int* in_sizes, int n_in,
                              void* d_out, int out_size, void* d_ws, size_t ws_size,
                              hipStream_t stream)
{
  const float* hs      = (const float*)d_in[0];
  const float* qkv_w   = (const float*)d_in[2];
  const float* qkv_b   = (const float*)d_in[3];
  const float* svd_tok = (const float*)d_in[4];
  const float* svd_qk  = (const float*)d_in[5];
  const float* svd_vl  = (const float*)d_in[6];
  const float* dense_w = (const float*)d_in[7];
  const float* dense_b = (const float*)d_in[8];
  float* out = (float*)d_out;
  bf16_t* ws = (bf16_t*)d_ws;

  bf16_t* hsb    = ws;                    //  4,194,304
  bf16_t* stb    = ws +  4194304LL;       //  4,194,304
  bf16_t* Mbuf   = ws +  8388608LL;       //  4,194,304
  bf16_t* x2     = ws + 12582912LL;       //  4,194,304
  bf16_t* qkv_wT = ws + 16777216LL;       // 12,582,912
  bf16_t* Wrot   = ws + 29360128LL;       // 12,582,912
  bf16_t* mixed  = ws + 41943040LL;       // 12,582,912
  bf16_t* vT     = ws + 54525952LL;       //  4,194,304
  bf16_t* ctx    = ws + 58720256LL;       //  4,194,304
  bf16_t* dwT    = ws + 62914560LL;       //  4,194,304
  bf16_t* tsrT   = ws + 67108864LL;       //  4,194,304
  bf16_t* qkT    = ws + 71303168LL;       //    262,144
  bf16_t* vlT    = ws + 71565312LL;       //    262,144
  bf16_t* brot   = ws + 71827456LL;       //      6,144
  if (ws_size < 71833600ULL * 2ULL) return;

  const float iscale = 0.08838834764831845f;   // 1/sqrt(128)

  // all memory-bound prep in one launch (one tile per block, no serial tail)
  front_k<<<dim3(18968), 256, 0, stream>>>(hs, hsb, svd_tok, stb,
      svd_qk, qkT, svd_vl, vlT, qkv_w, qkv_wT, dense_w, dwT, qkv_b, brot);
  // M GEMM (272 symmetric blocks, heavy-first) + Wrot/tsrT prep in one launch
  gemm_mprep<<<dim3(1296), 256, 0, stream>>>(qkT, vlT, qkv_wT, dwT,
      Wrot, tsrT, stb, Mbuf);
  // x2 = hs @ M  (M symmetric -> NT ok), BK=128, XCD col-chunked
  gemm_nt64k<<<dim3(16, 32), 256, 0, stream>>>(hsb, Mbuf, x2, nullptr,
      2048, 2048, 2048, 2048, 1.0f, 0);
  // mixed = x2 @ Wrot^T + brot  (128^2 tile, BK=64), XCD col-chunked
  gemm_nt128<<<dim3(48, 16), 256, 0, stream>>>(x2, Wrot, mixed, brot,
      2048, 2048, 2048, 6144, 1.0f, 8);
  // vT[h][e][t] = mixed[t][384h+256+e]
  transpose_b2b<<<dim3(64, 4, 16), 256, 0, stream>>>(mixed + 256, vT, 2048, 384, 6144, 262144);
  // fused attention -> ctx (balanced pairing + pipelined loads)
  flash_k<<<dim3(16, 32), 256, 0, stream>>>(mixed, vT, ctx, iscale);
  // out = ctx @ tsrT^T + dense_b  (f32 store), BK=128, XCD col-chunked
  gemm_nt64k<<<dim3(16, 32), 256, 0, stream>>>(ctx, tsrT, out, dense_b,
      2048, 2048, 2048, 2048, 1.0f, 4);
}